// Round 19
// baseline (591.460 us; speedup 1.0000x reference)
//
#include <hip/hip_runtime.h>
#include <hip/hip_bf16.h>

#define TSTEPS 28

typedef __attribute__((ext_vector_type(8))) short bf16x8;
typedef __attribute__((ext_vector_type(4))) float f32x4;
typedef __attribute__((ext_vector_type(4))) unsigned short u16x4;
typedef __hip_bfloat16 bf16;

__device__ __forceinline__ unsigned short f2b(float f) {
  bf16 h = __float2bfloat16(f);
  return *reinterpret_cast<unsigned short*>(&h);
}
__device__ __forceinline__ float b2f(unsigned short u) {
  bf16 h = *reinterpret_cast<bf16*>(&u);
  return __bfloat162float(h);
}

__device__ __forceinline__ void gload16(const void* g, void* l) {
  __builtin_amdgcn_global_load_lds(
      (const __attribute__((address_space(1))) void*)g,
      (__attribute__((address_space(3))) void*)l, 16, 0, 0);
}

__device__ __forceinline__ float sigm(float x) { return 1.f / (1.f + __expf(-x)); }
__device__ __forceinline__ float tanh_fast(float x) {
  const float e2 = __expf(2.f * x);
  return 1.f - 2.f / (e2 + 1.f);
}

__device__ __forceinline__ bf16x8 cvt8(const float* src) {
  const float4 v0 = *(const float4*)src;
  const float4 v1 = *(const float4*)(src + 4);
  bf16x8 sv;
  sv[0] = (short)f2b(v0.x); sv[1] = (short)f2b(v0.y);
  sv[2] = (short)f2b(v0.z); sv[3] = (short)f2b(v0.w);
  sv[4] = (short)f2b(v1.x); sv[5] = (short)f2b(v1.y);
  sv[6] = (short)f2b(v1.z); sv[7] = (short)f2b(v1.w);
  return sv;
}

// ---------------- f32 -> bf16 convert (vectorized) ----------------
__global__ void conv_kernel(const float* __restrict__ in, unsigned short* __restrict__ out, int n4) {
  int i = blockIdx.x * blockDim.x + threadIdx.x;
  const int stride = gridDim.x * blockDim.x;
  for (; i < n4; i += stride) {
    const float4 v = *(const float4*)&in[(size_t)i * 4];
    u16x4 o;
    o.x = f2b(v.x); o.y = f2b(v.y); o.z = f2b(v.z); o.w = f2b(v.w);
    *(u16x4*)&out[(size_t)i * 4] = o;
  }
}

// ---------------- fused whh pass: whhb = bf16(whh), whf[n][k] = bf16(sum_j whh[n][k+256j]) ----------------
__global__ __launch_bounds__(256) void convw_kernel(const float* __restrict__ whh,
                                                    unsigned short* __restrict__ whhb,
                                                    unsigned short* __restrict__ whf) {
  const int idx = blockIdx.x * 256 + threadIdx.x;  // 3072*64
  const int n = idx >> 6, k4 = (idx & 63) << 2;
  const float* r = &whh[(size_t)n * 1024 + k4];
  const float4 a = *(const float4*)r;
  const float4 b = *(const float4*)(r + 256);
  const float4 c = *(const float4*)(r + 512);
  const float4 d = *(const float4*)(r + 768);
  u16x4 oa, ob, oc, od, of;
  oa.x = f2b(a.x); oa.y = f2b(a.y); oa.z = f2b(a.z); oa.w = f2b(a.w);
  ob.x = f2b(b.x); ob.y = f2b(b.y); ob.z = f2b(b.z); ob.w = f2b(b.w);
  oc.x = f2b(c.x); oc.y = f2b(c.y); oc.z = f2b(c.z); oc.w = f2b(c.w);
  od.x = f2b(d.x); od.y = f2b(d.y); od.z = f2b(d.z); od.w = f2b(d.w);
  of.x = f2b(a.x + b.x + c.x + d.x);
  of.y = f2b(a.y + b.y + c.y + d.y);
  of.z = f2b(a.z + b.z + c.z + d.z);
  of.w = f2b(a.w + b.w + c.w + d.w);
  unsigned short* wb = &whhb[(size_t)n * 1024 + k4];
  *(u16x4*)(wb)       = oa;
  *(u16x4*)(wb + 256) = ob;
  *(u16x4*)(wb + 512) = oc;
  *(u16x4*)(wb + 768) = od;
  *(u16x4*)&whf[(size_t)n * 256 + k4] = of;
}

// ---------------- fc GEMM with fused f32->bf16 staging: x = z @ fc_w^T + b ----------------
__global__ __launch_bounds__(256, 2) void gemm_fc_kernel(
    const float* __restrict__ A, const float* __restrict__ W,
    const float* __restrict__ bias, float* __restrict__ out) {
  constexpr int K = 256, NT = K / 32;
  __shared__ __align__(16) bf16 lds[2][6144];
  const int tid = threadIdx.x;
  const int lane = tid & 63;
  const int l15 = lane & 15, l4 = lane >> 4;
  const int wid = tid >> 6, wm = wid >> 1, wn = wid & 1;
  const int m0 = blockIdx.x * 128, n0 = blockIdx.y * 64;
  const int ra = tid >> 2, cb = (tid & 3) * 8;

  f32x4 acc[4][2] = {};

  auto STAGE = [&](int buf, int kt) {
    const int k0 = kt * 32;
    *(bf16x8*)&lds[buf][tid * 8]        = cvt8(&A[(size_t)(m0 + ra) * K + k0 + cb]);
    *(bf16x8*)&lds[buf][2048 + tid * 8] = cvt8(&A[(size_t)(m0 + 64 + ra) * K + k0 + cb]);
    *(bf16x8*)&lds[buf][4096 + tid * 8] = cvt8(&W[(size_t)(n0 + ra) * K + k0 + cb]);
  };

  STAGE(0, 0);
  __syncthreads();
  for (int kt = 0; kt < NT; ++kt) {
    const int buf = kt & 1;
    if (kt + 1 < NT) STAGE(buf ^ 1, kt + 1);
    bf16x8 af[4], bfr[2];
#pragma unroll
    for (int m = 0; m < 4; ++m)
      af[m] = *(const bf16x8*)&lds[buf][(wm * 64 + m * 16 + l15) * 32 + l4 * 8];
#pragma unroll
    for (int n = 0; n < 2; ++n)
      bfr[n] = *(const bf16x8*)&lds[buf][4096 + (wn * 32 + n * 16 + l15) * 32 + l4 * 8];
#pragma unroll
    for (int m = 0; m < 4; ++m)
#pragma unroll
      for (int n = 0; n < 2; ++n)
        acc[m][n] = __builtin_amdgcn_mfma_f32_16x16x32_bf16(af[m], bfr[n], acc[m][n], 0, 0, 0);
    __syncthreads();
  }

#pragma unroll
  for (int m = 0; m < 4; ++m) {
#pragma unroll
    for (int n = 0; n < 2; ++n) {
      const int col = n0 + wn * 32 + n * 16 + l15;
      const int rowb = m0 + wm * 64 + m * 16 + l4 * 4;
      const float bv = bias[col];
#pragma unroll
      for (int r = 0; r < 4; ++r)
        out[(size_t)(rowb + r) * 1024 + col] = acc[m][n][r] + bv;
    }
  }
}

// ---------------- row LayerNorm -> h0b (bf16) + h0f (f32) ----------------
__global__ __launch_bounds__(256) void ln_kernel(const float* __restrict__ x,
                                                 const float* __restrict__ w,
                                                 const float* __restrict__ b,
                                                 bf16* __restrict__ h0b,
                                                 float* __restrict__ h0f) {
  const int row = blockIdx.x, tid = threadIdx.x;
  const float4 v = *(const float4*)&x[(size_t)row * 1024 + tid * 4];
  float vv[4] = {v.x, v.y, v.z, v.w};
  float s = vv[0] + vv[1] + vv[2] + vv[3];
  float sq = vv[0] * vv[0] + vv[1] * vv[1] + vv[2] * vv[2] + vv[3] * vv[3];
#pragma unroll
  for (int off = 32; off; off >>= 1) {
    s += __shfl_down(s, off);
    sq += __shfl_down(sq, off);
  }
  __shared__ float sa[4], sb[4];
  const int lane = tid & 63, wid = tid >> 6;
  if (lane == 0) { sa[wid] = s; sb[wid] = sq; }
  __syncthreads();
  s = sa[0] + sa[1] + sa[2] + sa[3];
  sq = sb[0] + sb[1] + sb[2] + sb[3];
  const float mu = s * (1.f / 1024.f);
  const float var = sq * (1.f / 1024.f) - mu * mu;
  const float rs = rsqrtf(var + 1e-5f);
#pragma unroll
  for (int j = 0; j < 4; ++j) {
    const int c = tid * 4 + j;
    const float xv = (vv[j] - mu) * rs * w[c] + b[c];
    h0b[(size_t)row * 1024 + c] = __float2bfloat16(xv);
    h0f[(size_t)row * 1024 + c] = xv;
  }
}

// ---------------- gi GEMM, 512 threads (8 waves), BM=64, 3x64 B-rows, BK=64 swizzled ----------------
__global__ __launch_bounds__(512, 4) void gemm_gi_kernel(
    const bf16* __restrict__ A,      // h0b [2048][1024] bf16
    const float* __restrict__ W,     // w_ih [3072][1024] f32
    const float* __restrict__ bias,  // [3072]
    unsigned short* __restrict__ out) {  // gib [2048][3072] bf16
  __shared__ __align__(16) bf16 lds[2][16384];
  const int tid = threadIdx.x;
  const int lane = tid & 63, l15 = lane & 15, l4 = lane >> 4;
  const int wid = tid >> 6, wm = wid >> 2, wn = wid & 3;
  const int n0 = blockIdx.x * 64, m0 = blockIdx.y * 64;

  f32x4 acc[3][2] = {};

  auto STAGE = [&](int buf, int kt) {
    const int k0 = kt * 64;
    {
      const int c = tid;
      const int row = c >> 3, kk = ((c & 7) ^ (row & 7)) * 8;
      gload16(&A[(size_t)(m0 + row) * 1024 + k0 + kk], &lds[buf][c * 8]);
    }
#pragma unroll
    for (int j = 0; j < 3; ++j) {
      const int c = tid + j * 512;
      const int row = c >> 3, kk = ((c & 7) ^ (row & 7)) * 8;
      *(bf16x8*)&lds[buf][4096 + c * 8] =
          cvt8(&W[(size_t)((row >> 6) * 1024 + n0 + (row & 63)) * 1024 + k0 + kk]);
    }
  };

  STAGE(0, 0);
  __syncthreads();
  for (int kt = 0; kt < 16; ++kt) {
    const int buf = kt & 1;
    if (kt + 1 < 16) STAGE(buf ^ 1, kt + 1);
#pragma unroll
    for (int ks = 0; ks < 2; ++ks) {
      const int x = (((ks << 2) | l4) ^ (l15 & 7)) * 8;
      bf16x8 af[2], bfr[3];
#pragma unroll
      for (int m = 0; m < 2; ++m)
        af[m] = *(const bf16x8*)&lds[buf][(wm * 32 + m * 16 + l15) * 64 + x];
#pragma unroll
      for (int g = 0; g < 3; ++g)
        bfr[g] = *(const bf16x8*)&lds[buf][4096 + (g * 64 + wn * 16 + l15) * 64 + x];
#pragma unroll
      for (int g = 0; g < 3; ++g)
#pragma unroll
        for (int m = 0; m < 2; ++m)
          acc[g][m] = __builtin_amdgcn_mfma_f32_16x16x32_bf16(af[m], bfr[g], acc[g][m], 0, 0, 0);
    }
    __syncthreads();
  }

  const int col = n0 + wn * 16 + l15;
#pragma unroll
  for (int g = 0; g < 3; ++g) {
    const float bv = bias[g * 1024 + col];
#pragma unroll
    for (int m = 0; m < 2; ++m) {
      const int rowb = m0 + wm * 32 + m * 16 + l4 * 4;
#pragma unroll
      for (int r = 0; r < 4; ++r)
        out[(size_t)(rowb + r) * 3072 + g * 1024 + col] = f2b(acc[g][m][r] + bv);
    }
  }
}

// ---------------- batched masked steps: 512 threads, K=256 folded whf, BK=64 swizzled ----------------
__global__ __launch_bounds__(512, 4) void batch_masked_kernel(
    const bf16* __restrict__ trueb,
    const int* __restrict__ tfmask,
    const bf16* __restrict__ whf,
    const float* __restrict__ bhh,
    const unsigned short* __restrict__ gib,
    float* __restrict__ out,
    bf16* __restrict__ hbt) {  // [28][2048][1024] bf16 or nullptr
  const int t = blockIdx.z;
  if (tfmask[t] == 0) return;
  __shared__ __align__(16) bf16 lds[2][16384];
  const int tid = threadIdx.x;
  const int lane = tid & 63, l15 = lane & 15, l4 = lane >> 4;
  const int wid = tid >> 6, wm = wid >> 2, wn = wid & 3;
  const int n0 = blockIdx.x * 64, m0 = blockIdx.y * 64;

  f32x4 acc[3][2] = {};

  auto STAGE = [&](int buf, int kt) {
    const int k0 = kt * 64;
    {
      const int c = tid;
      const int row = c >> 3, kk = ((c & 7) ^ (row & 7)) * 8;
      gload16(&trueb[((size_t)(m0 + row) * TSTEPS + t) * 256 + k0 + kk], &lds[buf][c * 8]);
    }
#pragma unroll
    for (int j = 0; j < 3; ++j) {
      const int c = tid + j * 512;
      const int row = c >> 3, kk = ((c & 7) ^ (row & 7)) * 8;
      gload16(&whf[(size_t)((row >> 6) * 1024 + n0 + (row & 63)) * 256 + k0 + kk],
              &lds[buf][4096 + c * 8]);
    }
  };

  STAGE(0, 0);
  __syncthreads();
  for (int kt = 0; kt < 4; ++kt) {
    const int buf = kt & 1;
    if (kt + 1 < 4) STAGE(buf ^ 1, kt + 1);
#pragma unroll
    for (int ks = 0; ks < 2; ++ks) {
      const int x = (((ks << 2) | l4) ^ (l15 & 7)) * 8;
      bf16x8 af[2], bfr[3];
#pragma unroll
      for (int m = 0; m < 2; ++m)
        af[m] = *(const bf16x8*)&lds[buf][(wm * 32 + m * 16 + l15) * 64 + x];
#pragma unroll
      for (int g = 0; g < 3; ++g)
        bfr[g] = *(const bf16x8*)&lds[buf][4096 + (g * 64 + wn * 16 + l15) * 64 + x];
#pragma unroll
      for (int g = 0; g < 3; ++g)
#pragma unroll
        for (int m = 0; m < 2; ++m)
          acc[g][m] = __builtin_amdgcn_mfma_f32_16x16x32_bf16(af[m], bfr[g], acc[g][m], 0, 0, 0);
    }
    __syncthreads();
  }

  float* outT = out + (size_t)t * 2048 * 1024;
  bf16* hbtT = hbt ? hbt + (size_t)t * 2048 * 1024 : nullptr;
  const int col = n0 + wn * 16 + l15;
  const float br = bhh[col], bz = bhh[col + 1024], bn_ = bhh[col + 2048];
  const unsigned short* tb = (const unsigned short*)trueb;
#pragma unroll
  for (int m = 0; m < 2; ++m) {
    const int rowb = m0 + wm * 32 + m * 16 + l4 * 4;
#pragma unroll
    for (int r = 0; r < 4; ++r) {
      const int row = rowb + r;
      const unsigned short* girow = &gib[(size_t)row * 3072];
      const float ir = b2f(girow[col]), iz = b2f(girow[col + 1024]), inn = b2f(girow[col + 2048]);
      const float hr = acc[0][m][r] + br;
      const float hz = acc[1][m][r] + bz;
      const float hn = acc[2][m][r] + bn_;
      const float hinv = b2f(tb[((size_t)row * TSTEPS + t) * 256 + (col & 255)]);
      const float rg = sigm(ir + hr);
      const float ug = sigm(iz + hz);
      const float ng = tanh_fast(inn + rg * hn);
      const float hnew = (1.f - ug) * ng + ug * hinv;
      outT[(size_t)row * 1024 + col] = hnew;
      if (hbtT) hbtT[(size_t)row * 1024 + col] = __float2bfloat16(hnew);
    }
  }
}

// ---------------- pipelined sequential step: 4 LDS bufs x BK=32, counted vmcnt (T3/T4) ----------------
// 512 threads, grid 512 XCD-swizzled, 2 blocks/CU. A always bf16 (hbt), 2 gload16/thread/STAGE.
__global__ __launch_bounds__(512, 2) void step2_kernel(
    const bf16* __restrict__ prevb,   // bf16 h[t-1] (h0b or hbt[t-1])
    const float* __restrict__ prevf,  // f32 h[t-1] for hinv
    bf16* __restrict__ hbtout,        // hbt[t]
    const int* __restrict__ tfmask,
    const bf16* __restrict__ whh,
    const float* __restrict__ bhh,
    const unsigned short* __restrict__ gib,
    float* __restrict__ out, int t) {
  if (tfmask[t] != 0) return;
  const int lid = blockIdx.x;
  const int xcd = lid & 7, rest = lid >> 3;
  const int m0 = (rest & 31) * 64;
  const int n0 = ((xcd << 1) | (rest >> 5)) * 64;

  __shared__ __align__(16) bf16 lds[4][8192];  // per buf: A 64x32 (2048) + B 192x32 (6144)
  const int tid = threadIdx.x;
  const int lane = tid & 63, l15 = lane & 15, l4 = lane >> 4;
  const int wid = tid >> 6, wm = wid >> 2, wn = wid & 3;

  f32x4 acc[3][2] = {};

  auto STAGE = [&](int buf, int kt) {
    const int k0 = kt * 32;
#pragma unroll
    for (int j = 0; j < 2; ++j) {
      const int c = tid + j * 512;
      if (c < 256) {
        const int row = c >> 2, kk = ((c & 3) ^ (row & 3)) * 8;
        gload16(&prevb[(size_t)(m0 + row) * 1024 + k0 + kk], &lds[buf][c * 8]);
      } else {
        const int bc = c - 256;
        const int row = bc >> 2, kk = ((bc & 3) ^ (row & 3)) * 8;
        gload16(&whh[(size_t)((row >> 6) * 1024 + n0 + (row & 63)) * 1024 + k0 + kk],
                &lds[buf][2048 + bc * 8]);
      }
    }
  };

  auto COMPUTE = [&](int buf) {
    const int x = (l4 ^ (l15 & 3)) * 8;
    bf16x8 af[2], bfr[3];
#pragma unroll
    for (int m = 0; m < 2; ++m)
      af[m] = *(const bf16x8*)&lds[buf][(wm * 32 + m * 16 + l15) * 32 + x];
#pragma unroll
    for (int g = 0; g < 3; ++g)
      bfr[g] = *(const bf16x8*)&lds[buf][2048 + (g * 64 + wn * 16 + l15) * 32 + x];
#pragma unroll
    for (int g = 0; g < 3; ++g)
#pragma unroll
      for (int m = 0; m < 2; ++m)
        acc[g][m] = __builtin_amdgcn_mfma_f32_16x16x32_bf16(af[m], bfr[g], acc[g][m], 0, 0, 0);
  };

  // prologue: 3 tiles in flight
  STAGE(0, 0);
  STAGE(1, 1);
  STAGE(2, 2);
  // main: at top of iter kt, 2 younger STAGEs (2 ops each) outstanding -> vmcnt(4)
  for (int kt = 0; kt < 30; ++kt) {
    asm volatile("s_waitcnt vmcnt(4)" ::: "memory");
    __builtin_amdgcn_s_barrier();
    __builtin_amdgcn_sched_barrier(0);
    COMPUTE(kt & 3);
    __builtin_amdgcn_sched_barrier(0);
    if (kt < 29) STAGE((kt + 3) & 3, kt + 3);
  }
  asm volatile("s_waitcnt vmcnt(2)" ::: "memory");
  __builtin_amdgcn_s_barrier();
  __builtin_amdgcn_sched_barrier(0);
  COMPUTE(30 & 3);
  asm volatile("s_waitcnt vmcnt(0)" ::: "memory");
  __builtin_amdgcn_s_barrier();
  __builtin_amdgcn_sched_barrier(0);
  COMPUTE(31 & 3);

  float* outT = out + (size_t)t * 2048 * 1024;
  const int col = n0 + wn * 16 + l15;
  const float br = bhh[col], bz = bhh[col + 1024], bn_ = bhh[col + 2048];
#pragma unroll
  for (int m = 0; m < 2; ++m) {
    const int rowb = m0 + wm * 32 + m * 16 + l4 * 4;
#pragma unroll
    for (int r = 0; r < 4; ++r) {
      const int row = rowb + r;
      const unsigned short* girow = &gib[(size_t)row * 3072];
      const float ir = b2f(girow[col]), iz = b2f(girow[col + 1024]), inn = b2f(girow[col + 2048]);
      const float hr = acc[0][m][r] + br;
      const float hz = acc[1][m][r] + bz;
      const float hn = acc[2][m][r] + bn_;
      const float hinv = prevf[(size_t)row * 1024 + col];
      const float rg = sigm(ir + hr);
      const float ug = sigm(iz + hz);
      const float ng = tanh_fast(inn + rg * hn);
      const float hnew = (1.f - ug) * ng + ug * hinv;
      outT[(size_t)row * 1024 + col] = hnew;
      hbtout[(size_t)row * 1024 + col] = __float2bfloat16(hnew);
    }
  }
}

// ---------------- fallback sequential step (R16, proven; used if ws too small for hbt) ----------------
__global__ __launch_bounds__(512, 4) void step_kernel(
    const float* __restrict__ prevf,
    const bf16* __restrict__ hbfprev,
    bf16* __restrict__ hbfout,
    const int* __restrict__ tfmask,
    const bf16* __restrict__ whh,
    const float* __restrict__ bhh,
    const unsigned short* __restrict__ gib,
    float* __restrict__ out, int t) {
  if (tfmask[t] != 0) return;
  const bool predf32 = (t == 0) || (tfmask[t - 1] != 0);
  const int lid = blockIdx.x;
  const int xcd = lid & 7, rest = lid >> 3;
  const int m0 = (rest & 31) * 64;
  const int n0 = ((xcd << 1) | (rest >> 5)) * 64;

  __shared__ __align__(16) bf16 lds[2][16384];
  const int tid = threadIdx.x;
  const int lane = tid & 63, l15 = lane & 15, l4 = lane >> 4;
  const int wid = tid >> 6, wm = wid >> 2, wn = wid & 3;

  f32x4 acc[3][2] = {};

  auto STAGE = [&](int buf, int kt) {
    const int k0 = kt * 64;
    {
      const int c = tid;
      const int row = c >> 3, kk = ((c & 7) ^ (row & 7)) * 8;
      if (predf32) {
        *(bf16x8*)&lds[buf][c * 8] = cvt8(&prevf[(size_t)(m0 + row) * 1024 + k0 + kk]);
      } else {
        gload16(&hbfprev[(size_t)(m0 + row) * 1024 + k0 + kk], &lds[buf][c * 8]);
      }
    }
#pragma unroll
    for (int j = 0; j < 3; ++j) {
      const int c = tid + j * 512;
      const int row = c >> 3, kk = ((c & 7) ^ (row & 7)) * 8;
      gload16(&whh[(size_t)((row >> 6) * 1024 + n0 + (row & 63)) * 1024 + k0 + kk],
              &lds[buf][4096 + c * 8]);
    }
  };

  STAGE(0, 0);
  __syncthreads();
  for (int kt = 0; kt < 16; ++kt) {
    const int buf = kt & 1;
    if (kt + 1 < 16) STAGE(buf ^ 1, kt + 1);
#pragma unroll
    for (int ks = 0; ks < 2; ++ks) {
      const int x = (((ks << 2) | l4) ^ (l15 & 7)) * 8;
      bf16x8 af[2], bfr[3];
#pragma unroll
      for (int m = 0; m < 2; ++m)
        af[m] = *(const bf16x8*)&lds[buf][(wm * 32 + m * 16 + l15) * 64 + x];
#pragma unroll
      for (int g = 0; g < 3; ++g)
        bfr[g] = *(const bf16x8*)&lds[buf][4096 + (g * 64 + wn * 16 + l15) * 64 + x];
#pragma unroll
      for (int g = 0; g < 3; ++g)
#pragma unroll
        for (int m = 0; m < 2; ++m)
          acc[g][m] = __builtin_amdgcn_mfma_f32_16x16x32_bf16(af[m], bfr[g], acc[g][m], 0, 0, 0);
    }
    __syncthreads();
  }

  float* outT = out + (size_t)t * 2048 * 1024;
  const int col = n0 + wn * 16 + l15;
  const float br = bhh[col], bz = bhh[col + 1024], bn_ = bhh[col + 2048];
#pragma unroll
  for (int m = 0; m < 2; ++m) {
    const int rowb = m0 + wm * 32 + m * 16 + l4 * 4;
#pragma unroll
    for (int r = 0; r < 4; ++r) {
      const int row = rowb + r;
      const unsigned short* girow = &gib[(size_t)row * 3072];
      const float ir = b2f(girow[col]), iz = b2f(girow[col + 1024]), inn = b2f(girow[col + 2048]);
      const float hr = acc[0][m][r] + br;
      const float hz = acc[1][m][r] + bz;
      const float hn = acc[2][m][r] + bn_;
      const float hinv = prevf[(size_t)row * 1024 + col];
      const float rg = sigm(ir + hr);
      const float ug = sigm(iz + hz);
      const float ng = tanh_fast(inn + rg * hn);
      const float hnew = (1.f - ug) * ng + ug * hinv;
      outT[(size_t)row * 1024 + col] = hnew;
      hbfout[(size_t)row * 1024 + col] = __float2bfloat16(hnew);
    }
  }
}

extern "C" void kernel_launch(void* const* d_in, const int* in_sizes, int n_in,
                              void* d_out, int out_size, void* d_ws, size_t ws_size,
                              hipStream_t stream) {
  (void)in_sizes; (void)n_in; (void)out_size;
  const float* z = (const float*)d_in[0];
  const float* trueinp = (const float*)d_in[1];
  const int* tfmask = (const int*)d_in[2];
  const float* fc_w = (const float*)d_in[3];
  const float* fc_b = (const float*)d_in[4];
  const float* ln_w = (const float*)d_in[5];
  const float* ln_b = (const float*)d_in[6];
  const float* w_ih = (const float*)d_in[7];
  const float* b_ih = (const float*)d_in[8];
  const float* w_hh = (const float*)d_in[9];
  const float* b_hh = (const float*)d_in[10];
  float* out = (float*)d_out;

  char* ws = (char*)d_ws;
  size_t o = 0;
  float* xraw = (float*)(ws + o); o += (size_t)2048 * 1024 * 4;
  float* h0f  = (float*)(ws + o); o += (size_t)2048 * 1024 * 4;
  unsigned short* gib = (unsigned short*)(ws + o); o += (size_t)2048 * 3072 * 2;
  bf16* h0b   = (bf16*)(ws + o);  o += (size_t)2048 * 1024 * 2;
  bf16* hbf0  = (bf16*)(ws + o);  o += (size_t)2048 * 1024 * 2;
  bf16* hbf1  = (bf16*)(ws + o);  o += (size_t)2048 * 1024 * 2;
  bf16* whhb  = (bf16*)(ws + o);  o += (size_t)3072 * 1024 * 2;
  bf16* whf   = (bf16*)(ws + o);  o += (size_t)3072 * 256 * 2;
  bf16* trueb = (bf16*)(ws + o);  o += (size_t)2048 * TSTEPS * 256 * 2;
  bf16* hbt   = (bf16*)(ws + o);
  const size_t need_hbt = o + (size_t)TSTEPS * 2048 * 1024 * 2;
  const bool use_hbt = (ws_size >= need_hbt);

  convw_kernel<<<768, 256, 0, stream>>>(w_hh, (unsigned short*)whhb, (unsigned short*)whf);
  conv_kernel<<<2048, 256, 0, stream>>>(trueinp, (unsigned short*)trueb, 2048 * TSTEPS * 256 / 4);

  gemm_fc_kernel<<<dim3(16, 16), 256, 0, stream>>>(z, fc_w, fc_b, xraw);
  ln_kernel<<<2048, 256, 0, stream>>>(xraw, ln_w, ln_b, h0b, h0f);
  gemm_gi_kernel<<<dim3(16, 32), 512, 0, stream>>>(h0b, w_ih, b_ih, gib);

  batch_masked_kernel<<<dim3(16, 32, TSTEPS), 512, 0, stream>>>(
      trueb, tfmask, whf, b_hh, gib, out, use_hbt ? hbt : nullptr);

  if (use_hbt) {
    for (int t = 0; t < TSTEPS; ++t) {
      const bf16* prevb = (t == 0) ? h0b : hbt + (size_t)(t - 1) * 2048 * 1024;
      const float* prevf = (t == 0) ? h0f : out + (size_t)(t - 1) * 2048 * 1024;
      bf16* hbtout = hbt + (size_t)t * 2048 * 1024;
      step2_kernel<<<512, 512, 0, stream>>>(prevb, prevf, hbtout, tfmask, whhb, b_hh,
                                            gib, out, t);
    }
  } else {
    const float* prev = h0f;
    for (int t = 0; t < TSTEPS; ++t) {
      bf16* hw = (t & 1) ? hbf1 : hbf0;
      const bf16* hr = (t & 1) ? hbf0 : hbf1;
      step_kernel<<<512, 512, 0, stream>>>(prev, hr, hw, tfmask, whhb, b_hh, gib, out, t);
      prev = out + (size_t)t * 2048 * 1024;
    }
  }
}

// Round 20
// 512.423 us; speedup vs baseline: 1.1542x; 1.1542x over previous
//
#include <hip/hip_runtime.h>
#include <hip/hip_bf16.h>

#define TSTEPS 28

typedef __attribute__((ext_vector_type(8))) short bf16x8;
typedef __attribute__((ext_vector_type(4))) float f32x4;
typedef __attribute__((ext_vector_type(4))) unsigned short u16x4;
typedef __hip_bfloat16 bf16;

__device__ __forceinline__ unsigned short f2b(float f) {
  bf16 h = __float2bfloat16(f);
  return *reinterpret_cast<unsigned short*>(&h);
}
__device__ __forceinline__ float b2f(unsigned short u) {
  bf16 h = *reinterpret_cast<bf16*>(&u);
  return __bfloat162float(h);
}

__device__ __forceinline__ void gload16(const void* g, void* l) {
  __builtin_amdgcn_global_load_lds(
      (const __attribute__((address_space(1))) void*)g,
      (__attribute__((address_space(3))) void*)l, 16, 0, 0);
}

__device__ __forceinline__ float sigm(float x) { return 1.f / (1.f + __expf(-x)); }
__device__ __forceinline__ float tanh_fast(float x) {
  const float e2 = __expf(2.f * x);
  return 1.f - 2.f / (e2 + 1.f);
}

__device__ __forceinline__ bf16x8 cvt8(const float* src) {
  const float4 v0 = *(const float4*)src;
  const float4 v1 = *(const float4*)(src + 4);
  bf16x8 sv;
  sv[0] = (short)f2b(v0.x); sv[1] = (short)f2b(v0.y);
  sv[2] = (short)f2b(v0.z); sv[3] = (short)f2b(v0.w);
  sv[4] = (short)f2b(v1.x); sv[5] = (short)f2b(v1.y);
  sv[6] = (short)f2b(v1.z); sv[7] = (short)f2b(v1.w);
  return sv;
}

// ---------------- f32 -> bf16 convert (vectorized) ----------------
__global__ void conv_kernel(const float* __restrict__ in, unsigned short* __restrict__ out, int n4) {
  int i = blockIdx.x * blockDim.x + threadIdx.x;
  const int stride = gridDim.x * blockDim.x;
  for (; i < n4; i += stride) {
    const float4 v = *(const float4*)&in[(size_t)i * 4];
    u16x4 o;
    o.x = f2b(v.x); o.y = f2b(v.y); o.z = f2b(v.z); o.w = f2b(v.w);
    *(u16x4*)&out[(size_t)i * 4] = o;
  }
}

// ---------------- fused whh pass: whhb = bf16(whh), whf[n][k] = bf16(sum_j whh[n][k+256j]) ----------------
__global__ __launch_bounds__(256) void convw_kernel(const float* __restrict__ whh,
                                                    unsigned short* __restrict__ whhb,
                                                    unsigned short* __restrict__ whf) {
  const int idx = blockIdx.x * 256 + threadIdx.x;  // 3072*64
  const int n = idx >> 6, k4 = (idx & 63) << 2;
  const float* r = &whh[(size_t)n * 1024 + k4];
  const float4 a = *(const float4*)r;
  const float4 b = *(const float4*)(r + 256);
  const float4 c = *(const float4*)(r + 512);
  const float4 d = *(const float4*)(r + 768);
  u16x4 oa, ob, oc, od, of;
  oa.x = f2b(a.x); oa.y = f2b(a.y); oa.z = f2b(a.z); oa.w = f2b(a.w);
  ob.x = f2b(b.x); ob.y = f2b(b.y); ob.z = f2b(b.z); ob.w = f2b(b.w);
  oc.x = f2b(c.x); oc.y = f2b(c.y); oc.z = f2b(c.z); oc.w = f2b(c.w);
  od.x = f2b(d.x); od.y = f2b(d.y); od.z = f2b(d.z); od.w = f2b(d.w);
  of.x = f2b(a.x + b.x + c.x + d.x);
  of.y = f2b(a.y + b.y + c.y + d.y);
  of.z = f2b(a.z + b.z + c.z + d.z);
  of.w = f2b(a.w + b.w + c.w + d.w);
  unsigned short* wb = &whhb[(size_t)n * 1024 + k4];
  *(u16x4*)(wb)       = oa;
  *(u16x4*)(wb + 256) = ob;
  *(u16x4*)(wb + 512) = oc;
  *(u16x4*)(wb + 768) = od;
  *(u16x4*)&whf[(size_t)n * 256 + k4] = of;
}

// ---------------- fc GEMM with fused f32->bf16 staging: x = z @ fc_w^T + b ----------------
__global__ __launch_bounds__(256, 2) void gemm_fc_kernel(
    const float* __restrict__ A, const float* __restrict__ W,
    const float* __restrict__ bias, float* __restrict__ out) {
  constexpr int K = 256, NT = K / 32;
  __shared__ __align__(16) bf16 lds[2][6144];
  const int tid = threadIdx.x;
  const int lane = tid & 63;
  const int l15 = lane & 15, l4 = lane >> 4;
  const int wid = tid >> 6, wm = wid >> 1, wn = wid & 1;
  const int m0 = blockIdx.x * 128, n0 = blockIdx.y * 64;
  const int ra = tid >> 2, cb = (tid & 3) * 8;

  f32x4 acc[4][2] = {};

  auto STAGE = [&](int buf, int kt) {
    const int k0 = kt * 32;
    *(bf16x8*)&lds[buf][tid * 8]        = cvt8(&A[(size_t)(m0 + ra) * K + k0 + cb]);
    *(bf16x8*)&lds[buf][2048 + tid * 8] = cvt8(&A[(size_t)(m0 + 64 + ra) * K + k0 + cb]);
    *(bf16x8*)&lds[buf][4096 + tid * 8] = cvt8(&W[(size_t)(n0 + ra) * K + k0 + cb]);
  };

  STAGE(0, 0);
  __syncthreads();
  for (int kt = 0; kt < NT; ++kt) {
    const int buf = kt & 1;
    if (kt + 1 < NT) STAGE(buf ^ 1, kt + 1);
    bf16x8 af[4], bfr[2];
#pragma unroll
    for (int m = 0; m < 4; ++m)
      af[m] = *(const bf16x8*)&lds[buf][(wm * 64 + m * 16 + l15) * 32 + l4 * 8];
#pragma unroll
    for (int n = 0; n < 2; ++n)
      bfr[n] = *(const bf16x8*)&lds[buf][4096 + (wn * 32 + n * 16 + l15) * 32 + l4 * 8];
#pragma unroll
    for (int m = 0; m < 4; ++m)
#pragma unroll
      for (int n = 0; n < 2; ++n)
        acc[m][n] = __builtin_amdgcn_mfma_f32_16x16x32_bf16(af[m], bfr[n], acc[m][n], 0, 0, 0);
    __syncthreads();
  }

#pragma unroll
  for (int m = 0; m < 4; ++m) {
#pragma unroll
    for (int n = 0; n < 2; ++n) {
      const int col = n0 + wn * 32 + n * 16 + l15;
      const int rowb = m0 + wm * 64 + m * 16 + l4 * 4;
      const float bv = bias[col];
#pragma unroll
      for (int r = 0; r < 4; ++r)
        out[(size_t)(rowb + r) * 1024 + col] = acc[m][n][r] + bv;
    }
  }
}

// ---------------- row LayerNorm -> h0b (bf16) + h0f (f32) ----------------
__global__ __launch_bounds__(256) void ln_kernel(const float* __restrict__ x,
                                                 const float* __restrict__ w,
                                                 const float* __restrict__ b,
                                                 bf16* __restrict__ h0b,
                                                 float* __restrict__ h0f) {
  const int row = blockIdx.x, tid = threadIdx.x;
  const float4 v = *(const float4*)&x[(size_t)row * 1024 + tid * 4];
  float vv[4] = {v.x, v.y, v.z, v.w};
  float s = vv[0] + vv[1] + vv[2] + vv[3];
  float sq = vv[0] * vv[0] + vv[1] * vv[1] + vv[2] * vv[2] + vv[3] * vv[3];
#pragma unroll
  for (int off = 32; off; off >>= 1) {
    s += __shfl_down(s, off);
    sq += __shfl_down(sq, off);
  }
  __shared__ float sa[4], sb[4];
  const int lane = tid & 63, wid = tid >> 6;
  if (lane == 0) { sa[wid] = s; sb[wid] = sq; }
  __syncthreads();
  s = sa[0] + sa[1] + sa[2] + sa[3];
  sq = sb[0] + sb[1] + sb[2] + sb[3];
  const float mu = s * (1.f / 1024.f);
  const float var = sq * (1.f / 1024.f) - mu * mu;
  const float rs = rsqrtf(var + 1e-5f);
#pragma unroll
  for (int j = 0; j < 4; ++j) {
    const int c = tid * 4 + j;
    const float xv = (vv[j] - mu) * rs * w[c] + b[c];
    h0b[(size_t)row * 1024 + c] = __float2bfloat16(xv);
    h0f[(size_t)row * 1024 + c] = xv;
  }
}

// ---------------- gi GEMM, 512 threads (8 waves), BM=64, 3x64 B-rows, BK=64 swizzled ----------------
__global__ __launch_bounds__(512, 4) void gemm_gi_kernel(
    const bf16* __restrict__ A,      // h0b [2048][1024] bf16
    const float* __restrict__ W,     // w_ih [3072][1024] f32
    const float* __restrict__ bias,  // [3072]
    unsigned short* __restrict__ out) {  // gib [2048][3072] bf16
  __shared__ __align__(16) bf16 lds[2][16384];
  const int tid = threadIdx.x;
  const int lane = tid & 63, l15 = lane & 15, l4 = lane >> 4;
  const int wid = tid >> 6, wm = wid >> 2, wn = wid & 3;
  const int n0 = blockIdx.x * 64, m0 = blockIdx.y * 64;

  f32x4 acc[3][2] = {};

  auto STAGE = [&](int buf, int kt) {
    const int k0 = kt * 64;
    {
      const int c = tid;
      const int row = c >> 3, kk = ((c & 7) ^ (row & 7)) * 8;
      gload16(&A[(size_t)(m0 + row) * 1024 + k0 + kk], &lds[buf][c * 8]);
    }
#pragma unroll
    for (int j = 0; j < 3; ++j) {
      const int c = tid + j * 512;
      const int row = c >> 3, kk = ((c & 7) ^ (row & 7)) * 8;
      *(bf16x8*)&lds[buf][4096 + c * 8] =
          cvt8(&W[(size_t)((row >> 6) * 1024 + n0 + (row & 63)) * 1024 + k0 + kk]);
    }
  };

  STAGE(0, 0);
  __syncthreads();
  for (int kt = 0; kt < 16; ++kt) {
    const int buf = kt & 1;
    if (kt + 1 < 16) STAGE(buf ^ 1, kt + 1);
#pragma unroll
    for (int ks = 0; ks < 2; ++ks) {
      const int x = (((ks << 2) | l4) ^ (l15 & 7)) * 8;
      bf16x8 af[2], bfr[3];
#pragma unroll
      for (int m = 0; m < 2; ++m)
        af[m] = *(const bf16x8*)&lds[buf][(wm * 32 + m * 16 + l15) * 64 + x];
#pragma unroll
      for (int g = 0; g < 3; ++g)
        bfr[g] = *(const bf16x8*)&lds[buf][4096 + (g * 64 + wn * 16 + l15) * 64 + x];
#pragma unroll
      for (int g = 0; g < 3; ++g)
#pragma unroll
        for (int m = 0; m < 2; ++m)
          acc[g][m] = __builtin_amdgcn_mfma_f32_16x16x32_bf16(af[m], bfr[g], acc[g][m], 0, 0, 0);
    }
    __syncthreads();
  }

  const int col = n0 + wn * 16 + l15;
#pragma unroll
  for (int g = 0; g < 3; ++g) {
    const float bv = bias[g * 1024 + col];
#pragma unroll
    for (int m = 0; m < 2; ++m) {
      const int rowb = m0 + wm * 32 + m * 16 + l4 * 4;
#pragma unroll
      for (int r = 0; r < 4; ++r)
        out[(size_t)(rowb + r) * 3072 + g * 1024 + col] = f2b(acc[g][m][r] + bv);
    }
  }
}

// ---------------- paired masked steps: 2 t per block share the whf B-tile ----------------
// grid (16 n, 32 m, 14 pairs), 512 threads. LDS 80KB/block -> 2 blocks/CU.
// Wave-uniform guards m1/m2; numerics per-t identical to single-t kernel.
__global__ __launch_bounds__(512, 2) void batch_pair_kernel(
    const bf16* __restrict__ trueb,   // [2048][28][256] bf16
    const int* __restrict__ tfmask,
    const bf16* __restrict__ whf,     // [3072][256] bf16
    const float* __restrict__ bhh,
    const unsigned short* __restrict__ gib,  // [2048][3072] bf16
    float* __restrict__ out) {
  const int p = blockIdx.z;
  const int t1 = 2 * p, t2 = 2 * p + 1;
  const bool m1 = tfmask[t1] != 0;
  const bool m2 = tfmask[t2] != 0;
  if (!m1 && !m2) return;
  __shared__ __align__(16) bf16 lds[2][20480];  // A1 4096 + A2 4096 + B 12288
  const int tid = threadIdx.x;
  const int lane = tid & 63, l15 = lane & 15, l4 = lane >> 4;
  const int wid = tid >> 6, wm = wid >> 2, wn = wid & 3;
  const int n0 = blockIdx.x * 64, m0 = blockIdx.y * 64;

  f32x4 acc1[3][2] = {}, acc2[3][2] = {};

  auto STAGE = [&](int buf, int kt) {
    const int k0 = kt * 64;
    {
      const int c = tid;
      const int row = c >> 3, kk = ((c & 7) ^ (row & 7)) * 8;
      if (m1)
        gload16(&trueb[((size_t)(m0 + row) * TSTEPS + t1) * 256 + k0 + kk], &lds[buf][c * 8]);
      if (m2)
        gload16(&trueb[((size_t)(m0 + row) * TSTEPS + t2) * 256 + k0 + kk],
                &lds[buf][4096 + c * 8]);
    }
#pragma unroll
    for (int j = 0; j < 3; ++j) {
      const int c = tid + j * 512;
      const int row = c >> 3, kk = ((c & 7) ^ (row & 7)) * 8;
      gload16(&whf[(size_t)((row >> 6) * 1024 + n0 + (row & 63)) * 256 + k0 + kk],
              &lds[buf][8192 + c * 8]);
    }
  };

  STAGE(0, 0);
  __syncthreads();
  for (int kt = 0; kt < 4; ++kt) {
    const int buf = kt & 1;
    if (kt + 1 < 4) STAGE(buf ^ 1, kt + 1);
#pragma unroll
    for (int ks = 0; ks < 2; ++ks) {
      const int x = (((ks << 2) | l4) ^ (l15 & 7)) * 8;
      bf16x8 bfr[3];
#pragma unroll
      for (int g = 0; g < 3; ++g)
        bfr[g] = *(const bf16x8*)&lds[buf][8192 + (g * 64 + wn * 16 + l15) * 64 + x];
      if (m1) {
        bf16x8 af[2];
#pragma unroll
        for (int m = 0; m < 2; ++m)
          af[m] = *(const bf16x8*)&lds[buf][(wm * 32 + m * 16 + l15) * 64 + x];
#pragma unroll
        for (int g = 0; g < 3; ++g)
#pragma unroll
          for (int m = 0; m < 2; ++m)
            acc1[g][m] = __builtin_amdgcn_mfma_f32_16x16x32_bf16(af[m], bfr[g], acc1[g][m], 0, 0, 0);
      }
      if (m2) {
        bf16x8 af[2];
#pragma unroll
        for (int m = 0; m < 2; ++m)
          af[m] = *(const bf16x8*)&lds[buf][4096 + (wm * 32 + m * 16 + l15) * 64 + x];
#pragma unroll
        for (int g = 0; g < 3; ++g)
#pragma unroll
          for (int m = 0; m < 2; ++m)
            acc2[g][m] = __builtin_amdgcn_mfma_f32_16x16x32_bf16(af[m], bfr[g], acc2[g][m], 0, 0, 0);
      }
    }
    __syncthreads();
  }

  const int col = n0 + wn * 16 + l15;
  const float br = bhh[col], bz = bhh[col + 1024], bn_ = bhh[col + 2048];
  const unsigned short* tb = (const unsigned short*)trueb;

  auto EPI = [&](int t, f32x4 (&acc)[3][2]) {
    float* outT = out + (size_t)t * 2048 * 1024;
#pragma unroll
    for (int m = 0; m < 2; ++m) {
      const int rowb = m0 + wm * 32 + m * 16 + l4 * 4;
#pragma unroll
      for (int r = 0; r < 4; ++r) {
        const int row = rowb + r;
        const unsigned short* girow = &gib[(size_t)row * 3072];
        const float ir = b2f(girow[col]), iz = b2f(girow[col + 1024]), inn = b2f(girow[col + 2048]);
        const float hr = acc[0][m][r] + br;
        const float hz = acc[1][m][r] + bz;
        const float hn = acc[2][m][r] + bn_;
        const float hinv = b2f(tb[((size_t)row * TSTEPS + t) * 256 + (col & 255)]);
        const float rg = sigm(ir + hr);
        const float ug = sigm(iz + hz);
        const float ng = tanh_fast(inn + rg * hn);
        outT[(size_t)row * 1024 + col] = (1.f - ug) * ng + ug * hinv;
      }
    }
  };
  if (m1) EPI(t1, acc1);
  if (m2) EPI(t2, acc2);
}

// ---------------- sequential step (R16 exact): 512 threads, dual A path, BK=64 swizzled ----------------
__global__ __launch_bounds__(512, 4) void step_kernel(
    const float* __restrict__ prevf,   // out[t-1] f32 (or h0f at t=0)
    const bf16* __restrict__ hbfprev,  // bf16 h[t-1] (valid iff pred unmasked)
    bf16* __restrict__ hbfout,         // bf16 h[t] destination
    const int* __restrict__ tfmask,
    const bf16* __restrict__ whh,      // [3072][1024] bf16
    const float* __restrict__ bhh,
    const unsigned short* __restrict__ gib,
    float* __restrict__ out, int t) {
  if (tfmask[t] != 0) return;
  const bool predf32 = (t == 0) || (tfmask[t - 1] != 0);
  const int lid = blockIdx.x;
  const int xcd = lid & 7, rest = lid >> 3;
  const int m0 = (rest & 31) * 64;
  const int n0 = ((xcd << 1) | (rest >> 5)) * 64;

  __shared__ __align__(16) bf16 lds[2][16384];  // A 64x64 + B 192x64
  const int tid = threadIdx.x;
  const int lane = tid & 63, l15 = lane & 15, l4 = lane >> 4;
  const int wid = tid >> 6, wm = wid >> 2, wn = wid & 3;

  f32x4 acc[3][2] = {};

  auto STAGE = [&](int buf, int kt) {
    const int k0 = kt * 64;
    {
      const int c = tid;
      const int row = c >> 3, kk = ((c & 7) ^ (row & 7)) * 8;
      if (predf32) {
        *(bf16x8*)&lds[buf][c * 8] = cvt8(&prevf[(size_t)(m0 + row) * 1024 + k0 + kk]);
      } else {
        gload16(&hbfprev[(size_t)(m0 + row) * 1024 + k0 + kk], &lds[buf][c * 8]);
      }
    }
#pragma unroll
    for (int j = 0; j < 3; ++j) {
      const int c = tid + j * 512;
      const int row = c >> 3, kk = ((c & 7) ^ (row & 7)) * 8;
      gload16(&whh[(size_t)((row >> 6) * 1024 + n0 + (row & 63)) * 1024 + k0 + kk],
              &lds[buf][4096 + c * 8]);
    }
  };

  STAGE(0, 0);
  __syncthreads();
  for (int kt = 0; kt < 16; ++kt) {
    const int buf = kt & 1;
    if (kt + 1 < 16) STAGE(buf ^ 1, kt + 1);
#pragma unroll
    for (int ks = 0; ks < 2; ++ks) {
      const int x = (((ks << 2) | l4) ^ (l15 & 7)) * 8;
      bf16x8 af[2], bfr[3];
#pragma unroll
      for (int m = 0; m < 2; ++m)
        af[m] = *(const bf16x8*)&lds[buf][(wm * 32 + m * 16 + l15) * 64 + x];
#pragma unroll
      for (int g = 0; g < 3; ++g)
        bfr[g] = *(const bf16x8*)&lds[buf][4096 + (g * 64 + wn * 16 + l15) * 64 + x];
#pragma unroll
      for (int g = 0; g < 3; ++g)
#pragma unroll
        for (int m = 0; m < 2; ++m)
          acc[g][m] = __builtin_amdgcn_mfma_f32_16x16x32_bf16(af[m], bfr[g], acc[g][m], 0, 0, 0);
    }
    __syncthreads();
  }

  float* outT = out + (size_t)t * 2048 * 1024;
  const int col = n0 + wn * 16 + l15;
  const float br = bhh[col], bz = bhh[col + 1024], bn_ = bhh[col + 2048];
#pragma unroll
  for (int m = 0; m < 2; ++m) {
    const int rowb = m0 + wm * 32 + m * 16 + l4 * 4;
#pragma unroll
    for (int r = 0; r < 4; ++r) {
      const int row = rowb + r;
      const unsigned short* girow = &gib[(size_t)row * 3072];
      const float ir = b2f(girow[col]), iz = b2f(girow[col + 1024]), inn = b2f(girow[col + 2048]);
      const float hr = acc[0][m][r] + br;
      const float hz = acc[1][m][r] + bz;
      const float hn = acc[2][m][r] + bn_;
      const float hinv = prevf[(size_t)row * 1024 + col];
      const float rg = sigm(ir + hr);
      const float ug = sigm(iz + hz);
      const float ng = tanh_fast(inn + rg * hn);
      const float hnew = (1.f - ug) * ng + ug * hinv;
      outT[(size_t)row * 1024 + col] = hnew;
      hbfout[(size_t)row * 1024 + col] = __float2bfloat16(hnew);
    }
  }
}

extern "C" void kernel_launch(void* const* d_in, const int* in_sizes, int n_in,
                              void* d_out, int out_size, void* d_ws, size_t ws_size,
                              hipStream_t stream) {
  (void)in_sizes; (void)n_in; (void)out_size; (void)ws_size;
  const float* z = (const float*)d_in[0];
  const float* trueinp = (const float*)d_in[1];
  const int* tfmask = (const int*)d_in[2];
  const float* fc_w = (const float*)d_in[3];
  const float* fc_b = (const float*)d_in[4];
  const float* ln_w = (const float*)d_in[5];
  const float* ln_b = (const float*)d_in[6];
  const float* w_ih = (const float*)d_in[7];
  const float* b_ih = (const float*)d_in[8];
  const float* w_hh = (const float*)d_in[9];
  const float* b_hh = (const float*)d_in[10];
  float* out = (float*)d_out;

  char* ws = (char*)d_ws;
  size_t o = 0;
  float* xraw = (float*)(ws + o); o += (size_t)2048 * 1024 * 4;
  float* h0f  = (float*)(ws + o); o += (size_t)2048 * 1024 * 4;
  unsigned short* gib = (unsigned short*)(ws + o); o += (size_t)2048 * 3072 * 2;
  bf16* h0b   = (bf16*)(ws + o);  o += (size_t)2048 * 1024 * 2;
  bf16* hbf0  = (bf16*)(ws + o);  o += (size_t)2048 * 1024 * 2;
  bf16* hbf1  = (bf16*)(ws + o);  o += (size_t)2048 * 1024 * 2;
  bf16* whhb  = (bf16*)(ws + o);  o += (size_t)3072 * 1024 * 2;
  bf16* whf   = (bf16*)(ws + o);  o += (size_t)3072 * 256 * 2;
  bf16* trueb = (bf16*)(ws + o);  o += (size_t)2048 * TSTEPS * 256 * 2;

  convw_kernel<<<768, 256, 0, stream>>>(w_hh, (unsigned short*)whhb, (unsigned short*)whf);
  conv_kernel<<<2048, 256, 0, stream>>>(trueinp, (unsigned short*)trueb, 2048 * TSTEPS * 256 / 4);

  gemm_fc_kernel<<<dim3(16, 16), 256, 0, stream>>>(z, fc_w, fc_b, xraw);
  ln_kernel<<<2048, 256, 0, stream>>>(xraw, ln_w, ln_b, h0b, h0f);
  gemm_gi_kernel<<<dim3(16, 32), 512, 0, stream>>>(h0b, w_ih, b_ih, gib);

  batch_pair_kernel<<<dim3(16, 32, TSTEPS / 2), 512, 0, stream>>>(trueb, tfmask, whf,
                                                                  b_hh, gib, out);

  const float* prev = h0f;
  for (int t = 0; t < TSTEPS; ++t) {
    bf16* hw = (t & 1) ? hbf1 : hbf0;
    const bf16* hr = (t & 1) ? hbf0 : hbf1;
    step_kernel<<<512, 512, 0, stream>>>(prev, hr, hw, tfmask, whhb, b_hh, gib, out, t);
    prev = out + (size_t)t * 2048 * 1024;
  }
}

// Round 21
// 510.240 us; speedup vs baseline: 1.1592x; 1.0043x over previous
//
#include <hip/hip_runtime.h>
#include <hip/hip_bf16.h>

#define TSTEPS 28

typedef __attribute__((ext_vector_type(8))) short bf16x8;
typedef __attribute__((ext_vector_type(4))) float f32x4;
typedef __attribute__((ext_vector_type(4))) unsigned short u16x4;
typedef __hip_bfloat16 bf16;

__device__ __forceinline__ unsigned short f2b(float f) {
  bf16 h = __float2bfloat16(f);
  return *reinterpret_cast<unsigned short*>(&h);
}
__device__ __forceinline__ float b2f(unsigned short u) {
  bf16 h = *reinterpret_cast<bf16*>(&u);
  return __bfloat162float(h);
}

__device__ __forceinline__ void gload16(const void* g, void* l) {
  __builtin_amdgcn_global_load_lds(
      (const __attribute__((address_space(1))) void*)g,
      (__attribute__((address_space(3))) void*)l, 16, 0, 0);
}

__device__ __forceinline__ float sigm(float x) { return 1.f / (1.f + __expf(-x)); }
__device__ __forceinline__ float tanh_fast(float x) {
  const float e2 = __expf(2.f * x);
  return 1.f - 2.f / (e2 + 1.f);
}

__device__ __forceinline__ bf16x8 cvt8(const float* src) {
  const float4 v0 = *(const float4*)src;
  const float4 v1 = *(const float4*)(src + 4);
  bf16x8 sv;
  sv[0] = (short)f2b(v0.x); sv[1] = (short)f2b(v0.y);
  sv[2] = (short)f2b(v0.z); sv[3] = (short)f2b(v0.w);
  sv[4] = (short)f2b(v1.x); sv[5] = (short)f2b(v1.y);
  sv[6] = (short)f2b(v1.z); sv[7] = (short)f2b(v1.w);
  return sv;
}

// ---------------- f32 -> bf16 convert (vectorized) ----------------
__global__ void conv_kernel(const float* __restrict__ in, unsigned short* __restrict__ out, int n4) {
  int i = blockIdx.x * blockDim.x + threadIdx.x;
  const int stride = gridDim.x * blockDim.x;
  for (; i < n4; i += stride) {
    const float4 v = *(const float4*)&in[(size_t)i * 4];
    u16x4 o;
    o.x = f2b(v.x); o.y = f2b(v.y); o.z = f2b(v.z); o.w = f2b(v.w);
    *(u16x4*)&out[(size_t)i * 4] = o;
  }
}

// ---------------- fused whh pass: whhb = bf16(whh), whf[n][k] = bf16(sum_j whh[n][k+256j]) ----------------
__global__ __launch_bounds__(256) void convw_kernel(const float* __restrict__ whh,
                                                    unsigned short* __restrict__ whhb,
                                                    unsigned short* __restrict__ whf) {
  const int idx = blockIdx.x * 256 + threadIdx.x;  // 3072*64
  const int n = idx >> 6, k4 = (idx & 63) << 2;
  const float* r = &whh[(size_t)n * 1024 + k4];
  const float4 a = *(const float4*)r;
  const float4 b = *(const float4*)(r + 256);
  const float4 c = *(const float4*)(r + 512);
  const float4 d = *(const float4*)(r + 768);
  u16x4 oa, ob, oc, od, of;
  oa.x = f2b(a.x); oa.y = f2b(a.y); oa.z = f2b(a.z); oa.w = f2b(a.w);
  ob.x = f2b(b.x); ob.y = f2b(b.y); ob.z = f2b(b.z); ob.w = f2b(b.w);
  oc.x = f2b(c.x); oc.y = f2b(c.y); oc.z = f2b(c.z); oc.w = f2b(c.w);
  od.x = f2b(d.x); od.y = f2b(d.y); od.z = f2b(d.z); od.w = f2b(d.w);
  of.x = f2b(a.x + b.x + c.x + d.x);
  of.y = f2b(a.y + b.y + c.y + d.y);
  of.z = f2b(a.z + b.z + c.z + d.z);
  of.w = f2b(a.w + b.w + c.w + d.w);
  unsigned short* wb = &whhb[(size_t)n * 1024 + k4];
  *(u16x4*)(wb)       = oa;
  *(u16x4*)(wb + 256) = ob;
  *(u16x4*)(wb + 512) = oc;
  *(u16x4*)(wb + 768) = od;
  *(u16x4*)&whf[(size_t)n * 256 + k4] = of;
}

// ---------------- fc GEMM with fused f32->bf16 staging: x = z @ fc_w^T + b ----------------
__global__ __launch_bounds__(256, 2) void gemm_fc_kernel(
    const float* __restrict__ A, const float* __restrict__ W,
    const float* __restrict__ bias, float* __restrict__ out) {
  constexpr int K = 256, NT = K / 32;
  __shared__ __align__(16) bf16 lds[2][6144];
  const int tid = threadIdx.x;
  const int lane = tid & 63;
  const int l15 = lane & 15, l4 = lane >> 4;
  const int wid = tid >> 6, wm = wid >> 1, wn = wid & 1;
  const int m0 = blockIdx.x * 128, n0 = blockIdx.y * 64;
  const int ra = tid >> 2, cb = (tid & 3) * 8;

  f32x4 acc[4][2] = {};

  auto STAGE = [&](int buf, int kt) {
    const int k0 = kt * 32;
    *(bf16x8*)&lds[buf][tid * 8]        = cvt8(&A[(size_t)(m0 + ra) * K + k0 + cb]);
    *(bf16x8*)&lds[buf][2048 + tid * 8] = cvt8(&A[(size_t)(m0 + 64 + ra) * K + k0 + cb]);
    *(bf16x8*)&lds[buf][4096 + tid * 8] = cvt8(&W[(size_t)(n0 + ra) * K + k0 + cb]);
  };

  STAGE(0, 0);
  __syncthreads();
  for (int kt = 0; kt < NT; ++kt) {
    const int buf = kt & 1;
    if (kt + 1 < NT) STAGE(buf ^ 1, kt + 1);
    bf16x8 af[4], bfr[2];
#pragma unroll
    for (int m = 0; m < 4; ++m)
      af[m] = *(const bf16x8*)&lds[buf][(wm * 64 + m * 16 + l15) * 32 + l4 * 8];
#pragma unroll
    for (int n = 0; n < 2; ++n)
      bfr[n] = *(const bf16x8*)&lds[buf][4096 + (wn * 32 + n * 16 + l15) * 32 + l4 * 8];
#pragma unroll
    for (int m = 0; m < 4; ++m)
#pragma unroll
      for (int n = 0; n < 2; ++n)
        acc[m][n] = __builtin_amdgcn_mfma_f32_16x16x32_bf16(af[m], bfr[n], acc[m][n], 0, 0, 0);
    __syncthreads();
  }

#pragma unroll
  for (int m = 0; m < 4; ++m) {
#pragma unroll
    for (int n = 0; n < 2; ++n) {
      const int col = n0 + wn * 32 + n * 16 + l15;
      const int rowb = m0 + wm * 64 + m * 16 + l4 * 4;
      const float bv = bias[col];
#pragma unroll
      for (int r = 0; r < 4; ++r)
        out[(size_t)(rowb + r) * 1024 + col] = acc[m][n][r] + bv;
    }
  }
}

// ---------------- row LayerNorm -> h0b (bf16) + h0f (f32) ----------------
__global__ __launch_bounds__(256) void ln_kernel(const float* __restrict__ x,
                                                 const float* __restrict__ w,
                                                 const float* __restrict__ b,
                                                 bf16* __restrict__ h0b,
                                                 float* __restrict__ h0f) {
  const int row = blockIdx.x, tid = threadIdx.x;
  const float4 v = *(const float4*)&x[(size_t)row * 1024 + tid * 4];
  float vv[4] = {v.x, v.y, v.z, v.w};
  float s = vv[0] + vv[1] + vv[2] + vv[3];
  float sq = vv[0] * vv[0] + vv[1] * vv[1] + vv[2] * vv[2] + vv[3] * vv[3];
#pragma unroll
  for (int off = 32; off; off >>= 1) {
    s += __shfl_down(s, off);
    sq += __shfl_down(sq, off);
  }
  __shared__ float sa[4], sb[4];
  const int lane = tid & 63, wid = tid >> 6;
  if (lane == 0) { sa[wid] = s; sb[wid] = sq; }
  __syncthreads();
  s = sa[0] + sa[1] + sa[2] + sa[3];
  sq = sb[0] + sb[1] + sb[2] + sb[3];
  const float mu = s * (1.f / 1024.f);
  const float var = sq * (1.f / 1024.f) - mu * mu;
  const float rs = rsqrtf(var + 1e-5f);
#pragma unroll
  for (int j = 0; j < 4; ++j) {
    const int c = tid * 4 + j;
    const float xv = (vv[j] - mu) * rs * w[c] + b[c];
    h0b[(size_t)row * 1024 + c] = __float2bfloat16(xv);
    h0f[(size_t)row * 1024 + c] = xv;
  }
}

// ---------------- gi GEMM, 512 threads (8 waves), BM=64, 3x64 B-rows, BK=64 swizzled ----------------
__global__ __launch_bounds__(512, 4) void gemm_gi_kernel(
    const bf16* __restrict__ A,      // h0b [2048][1024] bf16
    const float* __restrict__ W,     // w_ih [3072][1024] f32
    const float* __restrict__ bias,  // [3072]
    unsigned short* __restrict__ out) {  // gib [2048][3072] bf16
  __shared__ __align__(16) bf16 lds[2][16384];
  const int tid = threadIdx.x;
  const int lane = tid & 63, l15 = lane & 15, l4 = lane >> 4;
  const int wid = tid >> 6, wm = wid >> 2, wn = wid & 3;
  const int n0 = blockIdx.x * 64, m0 = blockIdx.y * 64;

  f32x4 acc[3][2] = {};

  auto STAGE = [&](int buf, int kt) {
    const int k0 = kt * 64;
    {
      const int c = tid;
      const int row = c >> 3, kk = ((c & 7) ^ (row & 7)) * 8;
      gload16(&A[(size_t)(m0 + row) * 1024 + k0 + kk], &lds[buf][c * 8]);
    }
#pragma unroll
    for (int j = 0; j < 3; ++j) {
      const int c = tid + j * 512;
      const int row = c >> 3, kk = ((c & 7) ^ (row & 7)) * 8;
      *(bf16x8*)&lds[buf][4096 + c * 8] =
          cvt8(&W[(size_t)((row >> 6) * 1024 + n0 + (row & 63)) * 1024 + k0 + kk]);
    }
  };

  STAGE(0, 0);
  __syncthreads();
  for (int kt = 0; kt < 16; ++kt) {
    const int buf = kt & 1;
    if (kt + 1 < 16) STAGE(buf ^ 1, kt + 1);
#pragma unroll
    for (int ks = 0; ks < 2; ++ks) {
      const int x = (((ks << 2) | l4) ^ (l15 & 7)) * 8;
      bf16x8 af[2], bfr[3];
#pragma unroll
      for (int m = 0; m < 2; ++m)
        af[m] = *(const bf16x8*)&lds[buf][(wm * 32 + m * 16 + l15) * 64 + x];
#pragma unroll
      for (int g = 0; g < 3; ++g)
        bfr[g] = *(const bf16x8*)&lds[buf][4096 + (g * 64 + wn * 16 + l15) * 64 + x];
#pragma unroll
      for (int g = 0; g < 3; ++g)
#pragma unroll
        for (int m = 0; m < 2; ++m)
          acc[g][m] = __builtin_amdgcn_mfma_f32_16x16x32_bf16(af[m], bfr[g], acc[g][m], 0, 0, 0);
    }
    __syncthreads();
  }

  const int col = n0 + wn * 16 + l15;
#pragma unroll
  for (int g = 0; g < 3; ++g) {
    const float bv = bias[g * 1024 + col];
#pragma unroll
    for (int m = 0; m < 2; ++m) {
      const int rowb = m0 + wm * 32 + m * 16 + l4 * 4;
#pragma unroll
      for (int r = 0; r < 4; ++r)
        out[(size_t)(rowb + r) * 3072 + g * 1024 + col] = f2b(acc[g][m][r] + bv);
    }
  }
}

// ---------------- paired masked steps: 2 t per block share the whf B-tile ----------------
__global__ __launch_bounds__(512, 2) void batch_pair_kernel(
    const bf16* __restrict__ trueb,   // [2048][28][256] bf16
    const int* __restrict__ tfmask,
    const bf16* __restrict__ whf,     // [3072][256] bf16
    const float* __restrict__ bhh,
    const unsigned short* __restrict__ gib,  // [2048][3072] bf16
    float* __restrict__ out) {
  const int p = blockIdx.z;
  const int t1 = 2 * p, t2 = 2 * p + 1;
  const bool m1 = tfmask[t1] != 0;
  const bool m2 = tfmask[t2] != 0;
  if (!m1 && !m2) return;
  __shared__ __align__(16) bf16 lds[2][20480];  // A1 4096 + A2 4096 + B 12288
  const int tid = threadIdx.x;
  const int lane = tid & 63, l15 = lane & 15, l4 = lane >> 4;
  const int wid = tid >> 6, wm = wid >> 2, wn = wid & 3;
  const int n0 = blockIdx.x * 64, m0 = blockIdx.y * 64;

  f32x4 acc1[3][2] = {}, acc2[3][2] = {};

  auto STAGE = [&](int buf, int kt) {
    const int k0 = kt * 64;
    {
      const int c = tid;
      const int row = c >> 3, kk = ((c & 7) ^ (row & 7)) * 8;
      if (m1)
        gload16(&trueb[((size_t)(m0 + row) * TSTEPS + t1) * 256 + k0 + kk], &lds[buf][c * 8]);
      if (m2)
        gload16(&trueb[((size_t)(m0 + row) * TSTEPS + t2) * 256 + k0 + kk],
                &lds[buf][4096 + c * 8]);
    }
#pragma unroll
    for (int j = 0; j < 3; ++j) {
      const int c = tid + j * 512;
      const int row = c >> 3, kk = ((c & 7) ^ (row & 7)) * 8;
      gload16(&whf[(size_t)((row >> 6) * 1024 + n0 + (row & 63)) * 256 + k0 + kk],
              &lds[buf][8192 + c * 8]);
    }
  };

  STAGE(0, 0);
  __syncthreads();
  for (int kt = 0; kt < 4; ++kt) {
    const int buf = kt & 1;
    if (kt + 1 < 4) STAGE(buf ^ 1, kt + 1);
#pragma unroll
    for (int ks = 0; ks < 2; ++ks) {
      const int x = (((ks << 2) | l4) ^ (l15 & 7)) * 8;
      bf16x8 bfr[3];
#pragma unroll
      for (int g = 0; g < 3; ++g)
        bfr[g] = *(const bf16x8*)&lds[buf][8192 + (g * 64 + wn * 16 + l15) * 64 + x];
      if (m1) {
        bf16x8 af[2];
#pragma unroll
        for (int m = 0; m < 2; ++m)
          af[m] = *(const bf16x8*)&lds[buf][(wm * 32 + m * 16 + l15) * 64 + x];
#pragma unroll
        for (int g = 0; g < 3; ++g)
#pragma unroll
          for (int m = 0; m < 2; ++m)
            acc1[g][m] = __builtin_amdgcn_mfma_f32_16x16x32_bf16(af[m], bfr[g], acc1[g][m], 0, 0, 0);
      }
      if (m2) {
        bf16x8 af[2];
#pragma unroll
        for (int m = 0; m < 2; ++m)
          af[m] = *(const bf16x8*)&lds[buf][4096 + (wm * 32 + m * 16 + l15) * 64 + x];
#pragma unroll
        for (int g = 0; g < 3; ++g)
#pragma unroll
          for (int m = 0; m < 2; ++m)
            acc2[g][m] = __builtin_amdgcn_mfma_f32_16x16x32_bf16(af[m], bfr[g], acc2[g][m], 0, 0, 0);
      }
    }
    __syncthreads();
  }

  const int col = n0 + wn * 16 + l15;
  const float br = bhh[col], bz = bhh[col + 1024], bn_ = bhh[col + 2048];
  const unsigned short* tb = (const unsigned short*)trueb;

  auto EPI = [&](int t, f32x4 (&acc)[3][2]) {
    float* outT = out + (size_t)t * 2048 * 1024;
#pragma unroll
    for (int m = 0; m < 2; ++m) {
      const int rowb = m0 + wm * 32 + m * 16 + l4 * 4;
#pragma unroll
      for (int r = 0; r < 4; ++r) {
        const int row = rowb + r;
        const unsigned short* girow = &gib[(size_t)row * 3072];
        const float ir = b2f(girow[col]), iz = b2f(girow[col + 1024]), inn = b2f(girow[col + 2048]);
        const float hr = acc[0][m][r] + br;
        const float hz = acc[1][m][r] + bz;
        const float hn = acc[2][m][r] + bn_;
        const float hinv = b2f(tb[((size_t)row * TSTEPS + t) * 256 + (col & 255)]);
        const float rg = sigm(ir + hr);
        const float ug = sigm(iz + hz);
        const float ng = tanh_fast(inn + rg * hn);
        outT[(size_t)row * 1024 + col] = (1.f - ug) * ng + ug * hinv;
      }
    }
  };
  if (m1) EPI(t1, acc1);
  if (m2) EPI(t2, acc2);
}

// ---------------- level-1 steps: unmasked t with masked predecessor (or t=0), all parallel ----------------
// grid (512, 28); early-exit unless level-1. A: t=0 -> h0b bf16; else cvt8(out[t-1]) (batch output).
// Writes out[t] ONLY (no hbf: same-parity level-1 writes would race; level-2 consumers use f32 path).
__global__ __launch_bounds__(512, 4) void level1_kernel(
    const bf16* __restrict__ h0b,
    const int* __restrict__ tfmask,
    const bf16* __restrict__ whh,      // [3072][1024] bf16
    const float* __restrict__ bhh,
    const unsigned short* __restrict__ gib,
    float* __restrict__ out) {
  const int t = blockIdx.y;
  if (tfmask[t] != 0) return;                         // masked -> batch
  if (t > 0 && tfmask[t - 1] == 0) return;            // level>=2 -> chain
  const float* prevf = (t == 0) ? nullptr : out + (size_t)(t - 1) * 2048 * 1024;

  const int lid = blockIdx.x;
  const int xcd = lid & 7, rest = lid >> 3;
  const int m0 = (rest & 31) * 64;
  const int n0 = ((xcd << 1) | (rest >> 5)) * 64;

  __shared__ __align__(16) bf16 lds[2][16384];  // A 64x64 + B 192x64
  const int tid = threadIdx.x;
  const int lane = tid & 63, l15 = lane & 15, l4 = lane >> 4;
  const int wid = tid >> 6, wm = wid >> 2, wn = wid & 3;

  f32x4 acc[3][2] = {};

  auto STAGE = [&](int buf, int kt) {
    const int k0 = kt * 64;
    {
      const int c = tid;
      const int row = c >> 3, kk = ((c & 7) ^ (row & 7)) * 8;
      if (t == 0) {
        gload16(&h0b[(size_t)(m0 + row) * 1024 + k0 + kk], &lds[buf][c * 8]);
      } else {
        *(bf16x8*)&lds[buf][c * 8] = cvt8(&prevf[(size_t)(m0 + row) * 1024 + k0 + kk]);
      }
    }
#pragma unroll
    for (int j = 0; j < 3; ++j) {
      const int c = tid + j * 512;
      const int row = c >> 3, kk = ((c & 7) ^ (row & 7)) * 8;
      gload16(&whh[(size_t)((row >> 6) * 1024 + n0 + (row & 63)) * 1024 + k0 + kk],
              &lds[buf][4096 + c * 8]);
    }
  };

  STAGE(0, 0);
  __syncthreads();
  for (int kt = 0; kt < 16; ++kt) {
    const int buf = kt & 1;
    if (kt + 1 < 16) STAGE(buf ^ 1, kt + 1);
#pragma unroll
    for (int ks = 0; ks < 2; ++ks) {
      const int x = (((ks << 2) | l4) ^ (l15 & 7)) * 8;
      bf16x8 af[2], bfr[3];
#pragma unroll
      for (int m = 0; m < 2; ++m)
        af[m] = *(const bf16x8*)&lds[buf][(wm * 32 + m * 16 + l15) * 64 + x];
#pragma unroll
      for (int g = 0; g < 3; ++g)
        bfr[g] = *(const bf16x8*)&lds[buf][4096 + (g * 64 + wn * 16 + l15) * 64 + x];
#pragma unroll
      for (int g = 0; g < 3; ++g)
#pragma unroll
        for (int m = 0; m < 2; ++m)
          acc[g][m] = __builtin_amdgcn_mfma_f32_16x16x32_bf16(af[m], bfr[g], acc[g][m], 0, 0, 0);
    }
    __syncthreads();
  }

  float* outT = out + (size_t)t * 2048 * 1024;
  const int col = n0 + wn * 16 + l15;
  const float br = bhh[col], bz = bhh[col + 1024], bn_ = bhh[col + 2048];
#pragma unroll
  for (int m = 0; m < 2; ++m) {
    const int rowb = m0 + wm * 32 + m * 16 + l4 * 4;
#pragma unroll
    for (int r = 0; r < 4; ++r) {
      const int row = rowb + r;
      const unsigned short* girow = &gib[(size_t)row * 3072];
      const float ir = b2f(girow[col]), iz = b2f(girow[col + 1024]), inn = b2f(girow[col + 2048]);
      const float hr = acc[0][m][r] + br;
      const float hz = acc[1][m][r] + bz;
      const float hn = acc[2][m][r] + bn_;
      float hinv;
      if (t == 0) {
        // h0f value == b2f of h0b's source; read f32 path via gib? No: epilogue needs exact h0f.
        // h0 row value: reconstruct from h0b would lose f32 precision vs reference path used before.
        // Use out-of-band: h0b is bf16(h0f); previous rounds used h0f here. Passed via whh? No:
        // For t==0 we pass prevf==nullptr; handle below with h0f pointer stored in bhh? Not safe.
        hinv = 0.f;  // overwritten: t==0 handled by separate arg (see launch: prevf != nullptr for t==0 too)
      } else {
        hinv = prevf[(size_t)row * 1024 + col];
      }
      const float rg = sigm(ir + hr);
      const float ug = sigm(iz + hz);
      const float ng = tanh_fast(inn + rg * hn);
      const float hnew = (1.f - ug) * ng + ug * hinv;
      outT[(size_t)row * 1024 + col] = hnew;
    }
  }
}

// level1 with explicit h0f for t==0 epilogue (keeps numerics identical to prior rounds)
__global__ __launch_bounds__(512, 4) void level1b_kernel(
    const bf16* __restrict__ h0b,
    const float* __restrict__ h0f,
    const int* __restrict__ tfmask,
    const bf16* __restrict__ whh,
    const float* __restrict__ bhh,
    const unsigned short* __restrict__ gib,
    float* __restrict__ out) {
  const int t = blockIdx.y;
  if (tfmask[t] != 0) return;
  if (t > 0 && tfmask[t - 1] == 0) return;
  const float* prevf = (t == 0) ? h0f : out + (size_t)(t - 1) * 2048 * 1024;
  const bool abf = (t == 0);

  const int lid = blockIdx.x;
  const int xcd = lid & 7, rest = lid >> 3;
  const int m0 = (rest & 31) * 64;
  const int n0 = ((xcd << 1) | (rest >> 5)) * 64;

  __shared__ __align__(16) bf16 lds[2][16384];
  const int tid = threadIdx.x;
  const int lane = tid & 63, l15 = lane & 15, l4 = lane >> 4;
  const int wid = tid >> 6, wm = wid >> 2, wn = wid & 3;

  f32x4 acc[3][2] = {};

  auto STAGE = [&](int buf, int kt) {
    const int k0 = kt * 64;
    {
      const int c = tid;
      const int row = c >> 3, kk = ((c & 7) ^ (row & 7)) * 8;
      if (abf) {
        gload16(&h0b[(size_t)(m0 + row) * 1024 + k0 + kk], &lds[buf][c * 8]);
      } else {
        *(bf16x8*)&lds[buf][c * 8] = cvt8(&prevf[(size_t)(m0 + row) * 1024 + k0 + kk]);
      }
    }
#pragma unroll
    for (int j = 0; j < 3; ++j) {
      const int c = tid + j * 512;
      const int row = c >> 3, kk = ((c & 7) ^ (row & 7)) * 8;
      gload16(&whh[(size_t)((row >> 6) * 1024 + n0 + (row & 63)) * 1024 + k0 + kk],
              &lds[buf][4096 + c * 8]);
    }
  };

  STAGE(0, 0);
  __syncthreads();
  for (int kt = 0; kt < 16; ++kt) {
    const int buf = kt & 1;
    if (kt + 1 < 16) STAGE(buf ^ 1, kt + 1);
#pragma unroll
    for (int ks = 0; ks < 2; ++ks) {
      const int x = (((ks << 2) | l4) ^ (l15 & 7)) * 8;
      bf16x8 af[2], bfr[3];
#pragma unroll
      for (int m = 0; m < 2; ++m)
        af[m] = *(const bf16x8*)&lds[buf][(wm * 32 + m * 16 + l15) * 64 + x];
#pragma unroll
      for (int g = 0; g < 3; ++g)
        bfr[g] = *(const bf16x8*)&lds[buf][4096 + (g * 64 + wn * 16 + l15) * 64 + x];
#pragma unroll
      for (int g = 0; g < 3; ++g)
#pragma unroll
        for (int m = 0; m < 2; ++m)
          acc[g][m] = __builtin_amdgcn_mfma_f32_16x16x32_bf16(af[m], bfr[g], acc[g][m], 0, 0, 0);
    }
    __syncthreads();
  }

  float* outT = out + (size_t)t * 2048 * 1024;
  const int col = n0 + wn * 16 + l15;
  const float br = bhh[col], bz = bhh[col + 1024], bn_ = bhh[col + 2048];
#pragma unroll
  for (int m = 0; m < 2; ++m) {
    const int rowb = m0 + wm * 32 + m * 16 + l4 * 4;
#pragma unroll
    for (int r = 0; r < 4; ++r) {
      const int row = rowb + r;
      const unsigned short* girow = &gib[(size_t)row * 3072];
      const float ir = b2f(girow[col]), iz = b2f(girow[col + 1024]), inn = b2f(girow[col + 2048]);
      const float hr = acc[0][m][r] + br;
      const float hz = acc[1][m][r] + bz;
      const float hn = acc[2][m][r] + bn_;
      const float hinv = prevf[(size_t)row * 1024 + col];
      const float rg = sigm(ir + hr);
      const float ug = sigm(iz + hz);
      const float ng = tanh_fast(inn + rg * hn);
      outT[(size_t)row * 1024 + col] = (1.f - ug) * ng + ug * hinv;
    }
  }
}

// ---------------- chain step (level>=2 only): dual A path, BK=64 swizzled ----------------
__global__ __launch_bounds__(512, 4) void step_kernel(
    const float* __restrict__ prevf,   // out[t-1] f32
    const bf16* __restrict__ hbfprev,  // bf16 h[t-1] (valid iff pred level>=2)
    bf16* __restrict__ hbfout,         // bf16 h[t] destination
    const int* __restrict__ tfmask,
    const bf16* __restrict__ whh,
    const float* __restrict__ bhh,
    const unsigned short* __restrict__ gib,
    float* __restrict__ out, int t) {
  if (tfmask[t] != 0) return;                       // masked -> batch
  if (tfmask[t - 1] != 0) return;                   // level-1 -> level1 kernel (t>=1 guaranteed)
  // pred t-1 is level-1 iff (t-1==0 || tfmask[t-2]!=0): its hbf was NOT written -> use f32 path
  const bool predf32 = (t == 1) || (tfmask[t - 2] != 0);
  const int lid = blockIdx.x;
  const int xcd = lid & 7, rest = lid >> 3;
  const int m0 = (rest & 31) * 64;
  const int n0 = ((xcd << 1) | (rest >> 5)) * 64;

  __shared__ __align__(16) bf16 lds[2][16384];
  const int tid = threadIdx.x;
  const int lane = tid & 63, l15 = lane & 15, l4 = lane >> 4;
  const int wid = tid >> 6, wm = wid >> 2, wn = wid & 3;

  f32x4 acc[3][2] = {};

  auto STAGE = [&](int buf, int kt) {
    const int k0 = kt * 64;
    {
      const int c = tid;
      const int row = c >> 3, kk = ((c & 7) ^ (row & 7)) * 8;
      if (predf32) {
        *(bf16x8*)&lds[buf][c * 8] = cvt8(&prevf[(size_t)(m0 + row) * 1024 + k0 + kk]);
      } else {
        gload16(&hbfprev[(size_t)(m0 + row) * 1024 + k0 + kk], &lds[buf][c * 8]);
      }
    }
#pragma unroll
    for (int j = 0; j < 3; ++j) {
      const int c = tid + j * 512;
      const int row = c >> 3, kk = ((c & 7) ^ (row & 7)) * 8;
      gload16(&whh[(size_t)((row >> 6) * 1024 + n0 + (row & 63)) * 1024 + k0 + kk],
              &lds[buf][4096 + c * 8]);
    }
  };

  STAGE(0, 0);
  __syncthreads();
  for (int kt = 0; kt < 16; ++kt) {
    const int buf = kt & 1;
    if (kt + 1 < 16) STAGE(buf ^ 1, kt + 1);
#pragma unroll
    for (int ks = 0; ks < 2; ++ks) {
      const int x = (((ks << 2) | l4) ^ (l15 & 7)) * 8;
      bf16x8 af[2], bfr[3];
#pragma unroll
      for (int m = 0; m < 2; ++m)
        af[m] = *(const bf16x8*)&lds[buf][(wm * 32 + m * 16 + l15) * 64 + x];
#pragma unroll
      for (int g = 0; g < 3; ++g)
        bfr[g] = *(const bf16x8*)&lds[buf][4096 + (g * 64 + wn * 16 + l15) * 64 + x];
#pragma unroll
      for (int g = 0; g < 3; ++g)
#pragma unroll
        for (int m = 0; m < 2; ++m)
          acc[g][m] = __builtin_amdgcn_mfma_f32_16x16x32_bf16(af[m], bfr[g], acc[g][m], 0, 0, 0);
    }
    __syncthreads();
  }

  float* outT = out + (size_t)t * 2048 * 1024;
  const int col = n0 + wn * 16 + l15;
  const float br = bhh[col], bz = bhh[col + 1024], bn_ = bhh[col + 2048];
#pragma unroll
  for (int m = 0; m < 2; ++m) {
    const int rowb = m0 + wm * 32 + m * 16 + l4 * 4;
#pragma unroll
    for (int r = 0; r < 4; ++r) {
      const int row = rowb + r;
      const unsigned short* girow = &gib[(size_t)row * 3072];
      const float ir = b2f(girow[col]), iz = b2f(girow[col + 1024]), inn = b2f(girow[col + 2048]);
      const float hr = acc[0][m][r] + br;
      const float hz = acc[1][m][r] + bz;
      const float hn = acc[2][m][r] + bn_;
      const float hinv = prevf[(size_t)row * 1024 + col];
      const float rg = sigm(ir + hr);
      const float ug = sigm(iz + hz);
      const float ng = tanh_fast(inn + rg * hn);
      const float hnew = (1.f - ug) * ng + ug * hinv;
      outT[(size_t)row * 1024 + col] = hnew;
      hbfout[(size_t)row * 1024 + col] = __float2bfloat16(hnew);
    }
  }
}

extern "C" void kernel_launch(void* const* d_in, const int* in_sizes, int n_in,
                              void* d_out, int out_size, void* d_ws, size_t ws_size,
                              hipStream_t stream) {
  (void)in_sizes; (void)n_in; (void)out_size; (void)ws_size;
  const float* z = (const float*)d_in[0];
  const float* trueinp = (const float*)d_in[1];
  const int* tfmask = (const int*)d_in[2];
  const float* fc_w = (const float*)d_in[3];
  const float* fc_b = (const float*)d_in[4];
  const float* ln_w = (const float*)d_in[5];
  const float* ln_b = (const float*)d_in[6];
  const float* w_ih = (const float*)d_in[7];
  const float* b_ih = (const float*)d_in[8];
  const float* w_hh = (const float*)d_in[9];
  const float* b_hh = (const float*)d_in[10];
  float* out = (float*)d_out;

  char* ws = (char*)d_ws;
  size_t o = 0;
  float* xraw = (float*)(ws + o); o += (size_t)2048 * 1024 * 4;
  float* h0f  = (float*)(ws + o); o += (size_t)2048 * 1024 * 4;
  unsigned short* gib = (unsigned short*)(ws + o); o += (size_t)2048 * 3072 * 2;
  bf16* h0b   = (bf16*)(ws + o);  o += (size_t)2048 * 1024 * 2;
  bf16* hbf0  = (bf16*)(ws + o);  o += (size_t)2048 * 1024 * 2;
  bf16* hbf1  = (bf16*)(ws + o);  o += (size_t)2048 * 1024 * 2;
  bf16* whhb  = (bf16*)(ws + o);  o += (size_t)3072 * 1024 * 2;
  bf16* whf   = (bf16*)(ws + o);  o += (size_t)3072 * 256 * 2;
  bf16* trueb = (bf16*)(ws + o);  o += (size_t)2048 * TSTEPS * 256 * 2;

  convw_kernel<<<768, 256, 0, stream>>>(w_hh, (unsigned short*)whhb, (unsigned short*)whf);
  conv_kernel<<<2048, 256, 0, stream>>>(trueinp, (unsigned short*)trueb, 2048 * TSTEPS * 256 / 4);

  gemm_fc_kernel<<<dim3(16, 16), 256, 0, stream>>>(z, fc_w, fc_b, xraw);
  ln_kernel<<<2048, 256, 0, stream>>>(xraw, ln_w, ln_b, h0b, h0f);
  gemm_gi_kernel<<<dim3(16, 32), 512, 0, stream>>>(h0b, w_ih, b_ih, gib);

  batch_pair_kernel<<<dim3(16, 32, TSTEPS / 2), 512, 0, stream>>>(trueb, tfmask, whf,
                                                                  b_hh, gib, out);

  level1b_kernel<<<dim3(512, TSTEPS), 512, 0, stream>>>(h0b, h0f, tfmask, whhb, b_hh,
                                                        gib, out);

  for (int t = 1; t < TSTEPS; ++t) {
    bf16* hw = (t & 1) ? hbf1 : hbf0;
    const bf16* hr = (t & 1) ? hbf0 : hbf1;
    const float* prev = out + (size_t)(t - 1) * 2048 * 1024;
    step_kernel<<<512, 512, 0, stream>>>(prev, hr, hw, tfmask, whhb, b_hh, gib, out, t);
  }
}

// Round 22
// 500.500 us; speedup vs baseline: 1.1817x; 1.0195x over previous
//
#include <hip/hip_runtime.h>
#include <hip/hip_bf16.h>

#define TSTEPS 28

typedef __attribute__((ext_vector_type(8))) short bf16x8;
typedef __attribute__((ext_vector_type(4))) float f32x4;
typedef __attribute__((ext_vector_type(4))) unsigned short u16x4;
typedef __hip_bfloat16 bf16;

__device__ __forceinline__ unsigned short f2b(float f) {
  bf16 h = __float2bfloat16(f);
  return *reinterpret_cast<unsigned short*>(&h);
}
__device__ __forceinline__ float b2f(unsigned short u) {
  bf16 h = *reinterpret_cast<bf16*>(&u);
  return __bfloat162float(h);
}

__device__ __forceinline__ void gload16(const void* g, void* l) {
  __builtin_amdgcn_global_load_lds(
      (const __attribute__((address_space(1))) void*)g,
      (__attribute__((address_space(3))) void*)l, 16, 0, 0);
}

__device__ __forceinline__ float sigm(float x) { return 1.f / (1.f + __expf(-x)); }
__device__ __forceinline__ float tanh_fast(float x) {
  const float e2 = __expf(2.f * x);
  return 1.f - 2.f / (e2 + 1.f);
}

__device__ __forceinline__ bf16x8 cvt8(const float* src) {
  const float4 v0 = *(const float4*)src;
  const float4 v1 = *(const float4*)(src + 4);
  bf16x8 sv;
  sv[0] = (short)f2b(v0.x); sv[1] = (short)f2b(v0.y);
  sv[2] = (short)f2b(v0.z); sv[3] = (short)f2b(v0.w);
  sv[4] = (short)f2b(v1.x); sv[5] = (short)f2b(v1.y);
  sv[6] = (short)f2b(v1.z); sv[7] = (short)f2b(v1.w);
  return sv;
}

// ---------------- f32 -> bf16 convert (vectorized) ----------------
__global__ void conv_kernel(const float* __restrict__ in, unsigned short* __restrict__ out, int n4) {
  int i = blockIdx.x * blockDim.x + threadIdx.x;
  const int stride = gridDim.x * blockDim.x;
  for (; i < n4; i += stride) {
    const float4 v = *(const float4*)&in[(size_t)i * 4];
    u16x4 o;
    o.x = f2b(v.x); o.y = f2b(v.y); o.z = f2b(v.z); o.w = f2b(v.w);
    *(u16x4*)&out[(size_t)i * 4] = o;
  }
}

// ---------------- fused whh pass: whhb = bf16(whh), whf[n][k] = bf16(sum_j whh[n][k+256j]) ----------------
__global__ __launch_bounds__(256) void convw_kernel(const float* __restrict__ whh,
                                                    unsigned short* __restrict__ whhb,
                                                    unsigned short* __restrict__ whf) {
  const int idx = blockIdx.x * 256 + threadIdx.x;  // 3072*64
  const int n = idx >> 6, k4 = (idx & 63) << 2;
  const float* r = &whh[(size_t)n * 1024 + k4];
  const float4 a = *(const float4*)r;
  const float4 b = *(const float4*)(r + 256);
  const float4 c = *(const float4*)(r + 512);
  const float4 d = *(const float4*)(r + 768);
  u16x4 oa, ob, oc, od, of;
  oa.x = f2b(a.x); oa.y = f2b(a.y); oa.z = f2b(a.z); oa.w = f2b(a.w);
  ob.x = f2b(b.x); ob.y = f2b(b.y); ob.z = f2b(b.z); ob.w = f2b(b.w);
  oc.x = f2b(c.x); oc.y = f2b(c.y); oc.z = f2b(c.z); oc.w = f2b(c.w);
  od.x = f2b(d.x); od.y = f2b(d.y); od.z = f2b(d.z); od.w = f2b(d.w);
  of.x = f2b(a.x + b.x + c.x + d.x);
  of.y = f2b(a.y + b.y + c.y + d.y);
  of.z = f2b(a.z + b.z + c.z + d.z);
  of.w = f2b(a.w + b.w + c.w + d.w);
  unsigned short* wb = &whhb[(size_t)n * 1024 + k4];
  *(u16x4*)(wb)       = oa;
  *(u16x4*)(wb + 256) = ob;
  *(u16x4*)(wb + 512) = oc;
  *(u16x4*)(wb + 768) = od;
  *(u16x4*)&whf[(size_t)n * 256 + k4] = of;
}

// ---------------- fc GEMM with fused f32->bf16 staging: x = z @ fc_w^T + b ----------------
__global__ __launch_bounds__(256, 2) void gemm_fc_kernel(
    const float* __restrict__ A, const float* __restrict__ W,
    const float* __restrict__ bias, float* __restrict__ out) {
  constexpr int K = 256, NT = K / 32;
  __shared__ __align__(16) bf16 lds[2][6144];
  const int tid = threadIdx.x;
  const int lane = tid & 63;
  const int l15 = lane & 15, l4 = lane >> 4;
  const int wid = tid >> 6, wm = wid >> 1, wn = wid & 1;
  const int m0 = blockIdx.x * 128, n0 = blockIdx.y * 64;
  const int ra = tid >> 2, cb = (tid & 3) * 8;

  f32x4 acc[4][2] = {};

  auto STAGE = [&](int buf, int kt) {
    const int k0 = kt * 32;
    *(bf16x8*)&lds[buf][tid * 8]        = cvt8(&A[(size_t)(m0 + ra) * K + k0 + cb]);
    *(bf16x8*)&lds[buf][2048 + tid * 8] = cvt8(&A[(size_t)(m0 + 64 + ra) * K + k0 + cb]);
    *(bf16x8*)&lds[buf][4096 + tid * 8] = cvt8(&W[(size_t)(n0 + ra) * K + k0 + cb]);
  };

  STAGE(0, 0);
  __syncthreads();
  for (int kt = 0; kt < NT; ++kt) {
    const int buf = kt & 1;
    if (kt + 1 < NT) STAGE(buf ^ 1, kt + 1);
    bf16x8 af[4], bfr[2];
#pragma unroll
    for (int m = 0; m < 4; ++m)
      af[m] = *(const bf16x8*)&lds[buf][(wm * 64 + m * 16 + l15) * 32 + l4 * 8];
#pragma unroll
    for (int n = 0; n < 2; ++n)
      bfr[n] = *(const bf16x8*)&lds[buf][4096 + (wn * 32 + n * 16 + l15) * 32 + l4 * 8];
#pragma unroll
    for (int m = 0; m < 4; ++m)
#pragma unroll
      for (int n = 0; n < 2; ++n)
        acc[m][n] = __builtin_amdgcn_mfma_f32_16x16x32_bf16(af[m], bfr[n], acc[m][n], 0, 0, 0);
    __syncthreads();
  }

#pragma unroll
  for (int m = 0; m < 4; ++m) {
#pragma unroll
    for (int n = 0; n < 2; ++n) {
      const int col = n0 + wn * 32 + n * 16 + l15;
      const int rowb = m0 + wm * 64 + m * 16 + l4 * 4;
      const float bv = bias[col];
#pragma unroll
      for (int r = 0; r < 4; ++r)
        out[(size_t)(rowb + r) * 1024 + col] = acc[m][n][r] + bv;
    }
  }
}

// ---------------- row LayerNorm -> h0b (bf16) + h0f (f32) ----------------
__global__ __launch_bounds__(256) void ln_kernel(const float* __restrict__ x,
                                                 const float* __restrict__ w,
                                                 const float* __restrict__ b,
                                                 bf16* __restrict__ h0b,
                                                 float* __restrict__ h0f) {
  const int row = blockIdx.x, tid = threadIdx.x;
  const float4 v = *(const float4*)&x[(size_t)row * 1024 + tid * 4];
  float vv[4] = {v.x, v.y, v.z, v.w};
  float s = vv[0] + vv[1] + vv[2] + vv[3];
  float sq = vv[0] * vv[0] + vv[1] * vv[1] + vv[2] * vv[2] + vv[3] * vv[3];
#pragma unroll
  for (int off = 32; off; off >>= 1) {
    s += __shfl_down(s, off);
    sq += __shfl_down(sq, off);
  }
  __shared__ float sa[4], sb[4];
  const int lane = tid & 63, wid = tid >> 6;
  if (lane == 0) { sa[wid] = s; sb[wid] = sq; }
  __syncthreads();
  s = sa[0] + sa[1] + sa[2] + sa[3];
  sq = sb[0] + sb[1] + sb[2] + sb[3];
  const float mu = s * (1.f / 1024.f);
  const float var = sq * (1.f / 1024.f) - mu * mu;
  const float rs = rsqrtf(var + 1e-5f);
#pragma unroll
  for (int j = 0; j < 4; ++j) {
    const int c = tid * 4 + j;
    const float xv = (vv[j] - mu) * rs * w[c] + b[c];
    h0b[(size_t)row * 1024 + c] = __float2bfloat16(xv);
    h0f[(size_t)row * 1024 + c] = xv;
  }
}

// ---------------- gi GEMM, 512 threads (8 waves), BM=64, 3x64 B-rows, BK=64 swizzled ----------------
__global__ __launch_bounds__(512, 4) void gemm_gi_kernel(
    const bf16* __restrict__ A,      // h0b [2048][1024] bf16
    const float* __restrict__ W,     // w_ih [3072][1024] f32
    const float* __restrict__ bias,  // [3072]
    unsigned short* __restrict__ out) {  // gib [2048][3072] bf16
  __shared__ __align__(16) bf16 lds[2][16384];
  const int tid = threadIdx.x;
  const int lane = tid & 63, l15 = lane & 15, l4 = lane >> 4;
  const int wid = tid >> 6, wm = wid >> 2, wn = wid & 3;
  const int n0 = blockIdx.x * 64, m0 = blockIdx.y * 64;

  f32x4 acc[3][2] = {};

  auto STAGE = [&](int buf, int kt) {
    const int k0 = kt * 64;
    {
      const int c = tid;
      const int row = c >> 3, kk = ((c & 7) ^ (row & 7)) * 8;
      gload16(&A[(size_t)(m0 + row) * 1024 + k0 + kk], &lds[buf][c * 8]);
    }
#pragma unroll
    for (int j = 0; j < 3; ++j) {
      const int c = tid + j * 512;
      const int row = c >> 3, kk = ((c & 7) ^ (row & 7)) * 8;
      *(bf16x8*)&lds[buf][4096 + c * 8] =
          cvt8(&W[(size_t)((row >> 6) * 1024 + n0 + (row & 63)) * 1024 + k0 + kk]);
    }
  };

  STAGE(0, 0);
  __syncthreads();
  for (int kt = 0; kt < 16; ++kt) {
    const int buf = kt & 1;
    if (kt + 1 < 16) STAGE(buf ^ 1, kt + 1);
#pragma unroll
    for (int ks = 0; ks < 2; ++ks) {
      const int x = (((ks << 2) | l4) ^ (l15 & 7)) * 8;
      bf16x8 af[2], bfr[3];
#pragma unroll
      for (int m = 0; m < 2; ++m)
        af[m] = *(const bf16x8*)&lds[buf][(wm * 32 + m * 16 + l15) * 64 + x];
#pragma unroll
      for (int g = 0; g < 3; ++g)
        bfr[g] = *(const bf16x8*)&lds[buf][4096 + (g * 64 + wn * 16 + l15) * 64 + x];
#pragma unroll
      for (int g = 0; g < 3; ++g)
#pragma unroll
        for (int m = 0; m < 2; ++m)
          acc[g][m] = __builtin_amdgcn_mfma_f32_16x16x32_bf16(af[m], bfr[g], acc[g][m], 0, 0, 0);
    }
    __syncthreads();
  }

  const int col = n0 + wn * 16 + l15;
#pragma unroll
  for (int g = 0; g < 3; ++g) {
    const float bv = bias[g * 1024 + col];
#pragma unroll
    for (int m = 0; m < 2; ++m) {
      const int rowb = m0 + wm * 32 + m * 16 + l4 * 4;
#pragma unroll
      for (int r = 0; r < 4; ++r)
        out[(size_t)(rowb + r) * 3072 + g * 1024 + col] = f2b(acc[g][m][r] + bv);
    }
  }
}

// ---------------- paired masked steps: 2 t per block share the whf B-tile; writes hbt bf16 ----------------
__global__ __launch_bounds__(512, 2) void batch_pair_kernel(
    const bf16* __restrict__ trueb,   // [2048][28][256] bf16
    const int* __restrict__ tfmask,
    const bf16* __restrict__ whf,     // [3072][256] bf16
    const float* __restrict__ bhh,
    const unsigned short* __restrict__ gib,  // [2048][3072] bf16
    float* __restrict__ out,
    bf16* __restrict__ hbt) {         // [28][2048][1024] bf16 or nullptr
  const int p = blockIdx.z;
  const int t1 = 2 * p, t2 = 2 * p + 1;
  const bool m1 = tfmask[t1] != 0;
  const bool m2 = tfmask[t2] != 0;
  if (!m1 && !m2) return;
  __shared__ __align__(16) bf16 lds[2][20480];  // A1 4096 + A2 4096 + B 12288
  const int tid = threadIdx.x;
  const int lane = tid & 63, l15 = lane & 15, l4 = lane >> 4;
  const int wid = tid >> 6, wm = wid >> 2, wn = wid & 3;
  const int n0 = blockIdx.x * 64, m0 = blockIdx.y * 64;

  f32x4 acc1[3][2] = {}, acc2[3][2] = {};

  auto STAGE = [&](int buf, int kt) {
    const int k0 = kt * 64;
    {
      const int c = tid;
      const int row = c >> 3, kk = ((c & 7) ^ (row & 7)) * 8;
      if (m1)
        gload16(&trueb[((size_t)(m0 + row) * TSTEPS + t1) * 256 + k0 + kk], &lds[buf][c * 8]);
      if (m2)
        gload16(&trueb[((size_t)(m0 + row) * TSTEPS + t2) * 256 + k0 + kk],
                &lds[buf][4096 + c * 8]);
    }
#pragma unroll
    for (int j = 0; j < 3; ++j) {
      const int c = tid + j * 512;
      const int row = c >> 3, kk = ((c & 7) ^ (row & 7)) * 8;
      gload16(&whf[(size_t)((row >> 6) * 1024 + n0 + (row & 63)) * 256 + k0 + kk],
              &lds[buf][8192 + c * 8]);
    }
  };

  STAGE(0, 0);
  __syncthreads();
  for (int kt = 0; kt < 4; ++kt) {
    const int buf = kt & 1;
    if (kt + 1 < 4) STAGE(buf ^ 1, kt + 1);
#pragma unroll
    for (int ks = 0; ks < 2; ++ks) {
      const int x = (((ks << 2) | l4) ^ (l15 & 7)) * 8;
      bf16x8 bfr[3];
#pragma unroll
      for (int g = 0; g < 3; ++g)
        bfr[g] = *(const bf16x8*)&lds[buf][8192 + (g * 64 + wn * 16 + l15) * 64 + x];
      if (m1) {
        bf16x8 af[2];
#pragma unroll
        for (int m = 0; m < 2; ++m)
          af[m] = *(const bf16x8*)&lds[buf][(wm * 32 + m * 16 + l15) * 64 + x];
#pragma unroll
        for (int g = 0; g < 3; ++g)
#pragma unroll
          for (int m = 0; m < 2; ++m)
            acc1[g][m] = __builtin_amdgcn_mfma_f32_16x16x32_bf16(af[m], bfr[g], acc1[g][m], 0, 0, 0);
      }
      if (m2) {
        bf16x8 af[2];
#pragma unroll
        for (int m = 0; m < 2; ++m)
          af[m] = *(const bf16x8*)&lds[buf][4096 + (wm * 32 + m * 16 + l15) * 64 + x];
#pragma unroll
        for (int g = 0; g < 3; ++g)
#pragma unroll
          for (int m = 0; m < 2; ++m)
            acc2[g][m] = __builtin_amdgcn_mfma_f32_16x16x32_bf16(af[m], bfr[g], acc2[g][m], 0, 0, 0);
      }
    }
    __syncthreads();
  }

  const int col = n0 + wn * 16 + l15;
  const float br = bhh[col], bz = bhh[col + 1024], bn_ = bhh[col + 2048];
  const unsigned short* tb = (const unsigned short*)trueb;

  auto EPI = [&](int t, f32x4 (&acc)[3][2]) {
    float* outT = out + (size_t)t * 2048 * 1024;
    bf16* hbtT = hbt ? hbt + (size_t)t * 2048 * 1024 : nullptr;
#pragma unroll
    for (int m = 0; m < 2; ++m) {
      const int rowb = m0 + wm * 32 + m * 16 + l4 * 4;
#pragma unroll
      for (int r = 0; r < 4; ++r) {
        const int row = rowb + r;
        const unsigned short* girow = &gib[(size_t)row * 3072];
        const float ir = b2f(girow[col]), iz = b2f(girow[col + 1024]), inn = b2f(girow[col + 2048]);
        const float hr = acc[0][m][r] + br;
        const float hz = acc[1][m][r] + bz;
        const float hn = acc[2][m][r] + bn_;
        const float hinv = b2f(tb[((size_t)row * TSTEPS + t) * 256 + (col & 255)]);
        const float rg = sigm(ir + hr);
        const float ug = sigm(iz + hz);
        const float ng = tanh_fast(inn + rg * hn);
        const float hnew = (1.f - ug) * ng + ug * hinv;
        outT[(size_t)row * 1024 + col] = hnew;
        if (hbtT) hbtT[(size_t)row * 1024 + col] = __float2bfloat16(hnew);
      }
    }
  };
  if (m1) EPI(t1, acc1);
  if (m2) EPI(t2, acc2);
}

// ---------------- level-1 steps (unmasked t, masked pred or t=0), all parallel ----------------
// A from bf16: h0b (t=0) or hbt[t-1] (batch output) via gload16; fallback cvt8(out[t-1]) if no hbt.
// Writes out[t] ONLY (level-2 consumers use the f32 path; bit-identical rounding).
__global__ __launch_bounds__(512, 4) void level1b_kernel(
    const bf16* __restrict__ h0b,
    const float* __restrict__ h0f,
    const bf16* __restrict__ hbt,      // [28][2048][1024] bf16 or nullptr
    const int* __restrict__ tfmask,
    const bf16* __restrict__ whh,
    const float* __restrict__ bhh,
    const unsigned short* __restrict__ gib,
    float* __restrict__ out) {
  const int t = blockIdx.y;
  if (tfmask[t] != 0) return;
  if (t > 0 && tfmask[t - 1] == 0) return;
  const float* prevf = (t == 0) ? h0f : out + (size_t)(t - 1) * 2048 * 1024;
  const bf16* prevb = (t == 0) ? h0b : (hbt ? hbt + (size_t)(t - 1) * 2048 * 1024 : nullptr);

  const int lid = blockIdx.x;
  const int xcd = lid & 7, rest = lid >> 3;
  const int m0 = (rest & 31) * 64;
  const int n0 = ((xcd << 1) | (rest >> 5)) * 64;

  __shared__ __align__(16) bf16 lds[2][16384];
  const int tid = threadIdx.x;
  const int lane = tid & 63, l15 = lane & 15, l4 = lane >> 4;
  const int wid = tid >> 6, wm = wid >> 2, wn = wid & 3;

  f32x4 acc[3][2] = {};

  auto STAGE = [&](int buf, int kt) {
    const int k0 = kt * 64;
    {
      const int c = tid;
      const int row = c >> 3, kk = ((c & 7) ^ (row & 7)) * 8;
      if (prevb) {
        gload16(&prevb[(size_t)(m0 + row) * 1024 + k0 + kk], &lds[buf][c * 8]);
      } else {
        *(bf16x8*)&lds[buf][c * 8] = cvt8(&prevf[(size_t)(m0 + row) * 1024 + k0 + kk]);
      }
    }
#pragma unroll
    for (int j = 0; j < 3; ++j) {
      const int c = tid + j * 512;
      const int row = c >> 3, kk = ((c & 7) ^ (row & 7)) * 8;
      gload16(&whh[(size_t)((row >> 6) * 1024 + n0 + (row & 63)) * 1024 + k0 + kk],
              &lds[buf][4096 + c * 8]);
    }
  };

  STAGE(0, 0);
  __syncthreads();
  for (int kt = 0; kt < 16; ++kt) {
    const int buf = kt & 1;
    if (kt + 1 < 16) STAGE(buf ^ 1, kt + 1);
#pragma unroll
    for (int ks = 0; ks < 2; ++ks) {
      const int x = (((ks << 2) | l4) ^ (l15 & 7)) * 8;
      bf16x8 af[2], bfr[3];
#pragma unroll
      for (int m = 0; m < 2; ++m)
        af[m] = *(const bf16x8*)&lds[buf][(wm * 32 + m * 16 + l15) * 64 + x];
#pragma unroll
      for (int g = 0; g < 3; ++g)
        bfr[g] = *(const bf16x8*)&lds[buf][4096 + (g * 64 + wn * 16 + l15) * 64 + x];
#pragma unroll
      for (int g = 0; g < 3; ++g)
#pragma unroll
        for (int m = 0; m < 2; ++m)
          acc[g][m] = __builtin_amdgcn_mfma_f32_16x16x32_bf16(af[m], bfr[g], acc[g][m], 0, 0, 0);
    }
    __syncthreads();
  }

  float* outT = out + (size_t)t * 2048 * 1024;
  const int col = n0 + wn * 16 + l15;
  const float br = bhh[col], bz = bhh[col + 1024], bn_ = bhh[col + 2048];
#pragma unroll
  for (int m = 0; m < 2; ++m) {
    const int rowb = m0 + wm * 32 + m * 16 + l4 * 4;
#pragma unroll
    for (int r = 0; r < 4; ++r) {
      const int row = rowb + r;
      const unsigned short* girow = &gib[(size_t)row * 3072];
      const float ir = b2f(girow[col]), iz = b2f(girow[col + 1024]), inn = b2f(girow[col + 2048]);
      const float hr = acc[0][m][r] + br;
      const float hz = acc[1][m][r] + bz;
      const float hn = acc[2][m][r] + bn_;
      const float hinv = prevf[(size_t)row * 1024 + col];
      const float rg = sigm(ir + hr);
      const float ug = sigm(iz + hz);
      const float ng = tanh_fast(inn + rg * hn);
      outT[(size_t)row * 1024 + col] = (1.f - ug) * ng + ug * hinv;
    }
  }
}

// ---------------- chain step (level>=2 only): dual A path, BK=64 swizzled ----------------
__global__ __launch_bounds__(512, 4) void step_kernel(
    const float* __restrict__ prevf,   // out[t-1] f32
    const bf16* __restrict__ hbfprev,  // bf16 h[t-1] (valid iff pred level>=2)
    bf16* __restrict__ hbfout,         // bf16 h[t] destination
    const int* __restrict__ tfmask,
    const bf16* __restrict__ whh,
    const float* __restrict__ bhh,
    const unsigned short* __restrict__ gib,
    float* __restrict__ out, int t) {
  if (tfmask[t] != 0) return;                       // masked -> batch
  if (tfmask[t - 1] != 0) return;                   // level-1 -> level1 kernel (t>=1 guaranteed)
  // pred t-1 is level-1 iff (t-1==0 || tfmask[t-2]!=0): its hbf was NOT written -> use f32 path
  const bool predf32 = (t == 1) || (tfmask[t - 2] != 0);
  const int lid = blockIdx.x;
  const int xcd = lid & 7, rest = lid >> 3;
  const int m0 = (rest & 31) * 64;
  const int n0 = ((xcd << 1) | (rest >> 5)) * 64;

  __shared__ __align__(16) bf16 lds[2][16384];
  const int tid = threadIdx.x;
  const int lane = tid & 63, l15 = lane & 15, l4 = lane >> 4;
  const int wid = tid >> 6, wm = wid >> 2, wn = wid & 3;

  f32x4 acc[3][2] = {};

  auto STAGE = [&](int buf, int kt) {
    const int k0 = kt * 64;
    {
      const int c = tid;
      const int row = c >> 3, kk = ((c & 7) ^ (row & 7)) * 8;
      if (predf32) {
        *(bf16x8*)&lds[buf][c * 8] = cvt8(&prevf[(size_t)(m0 + row) * 1024 + k0 + kk]);
      } else {
        gload16(&hbfprev[(size_t)(m0 + row) * 1024 + k0 + kk], &lds[buf][c * 8]);
      }
    }
#pragma unroll
    for (int j = 0; j < 3; ++j) {
      const int c = tid + j * 512;
      const int row = c >> 3, kk = ((c & 7) ^ (row & 7)) * 8;
      gload16(&whh[(size_t)((row >> 6) * 1024 + n0 + (row & 63)) * 1024 + k0 + kk],
              &lds[buf][4096 + c * 8]);
    }
  };

  STAGE(0, 0);
  __syncthreads();
  for (int kt = 0; kt < 16; ++kt) {
    const int buf = kt & 1;
    if (kt + 1 < 16) STAGE(buf ^ 1, kt + 1);
#pragma unroll
    for (int ks = 0; ks < 2; ++ks) {
      const int x = (((ks << 2) | l4) ^ (l15 & 7)) * 8;
      bf16x8 af[2], bfr[3];
#pragma unroll
      for (int m = 0; m < 2; ++m)
        af[m] = *(const bf16x8*)&lds[buf][(wm * 32 + m * 16 + l15) * 64 + x];
#pragma unroll
      for (int g = 0; g < 3; ++g)
        bfr[g] = *(const bf16x8*)&lds[buf][4096 + (g * 64 + wn * 16 + l15) * 64 + x];
#pragma unroll
      for (int g = 0; g < 3; ++g)
#pragma unroll
        for (int m = 0; m < 2; ++m)
          acc[g][m] = __builtin_amdgcn_mfma_f32_16x16x32_bf16(af[m], bfr[g], acc[g][m], 0, 0, 0);
    }
    __syncthreads();
  }

  float* outT = out + (size_t)t * 2048 * 1024;
  const int col = n0 + wn * 16 + l15;
  const float br = bhh[col], bz = bhh[col + 1024], bn_ = bhh[col + 2048];
#pragma unroll
  for (int m = 0; m < 2; ++m) {
    const int rowb = m0 + wm * 32 + m * 16 + l4 * 4;
#pragma unroll
    for (int r = 0; r < 4; ++r) {
      const int row = rowb + r;
      const unsigned short* girow = &gib[(size_t)row * 3072];
      const float ir = b2f(girow[col]), iz = b2f(girow[col + 1024]), inn = b2f(girow[col + 2048]);
      const float hr = acc[0][m][r] + br;
      const float hz = acc[1][m][r] + bz;
      const float hn = acc[2][m][r] + bn_;
      const float hinv = prevf[(size_t)row * 1024 + col];
      const float rg = sigm(ir + hr);
      const float ug = sigm(iz + hz);
      const float ng = tanh_fast(inn + rg * hn);
      const float hnew = (1.f - ug) * ng + ug * hinv;
      outT[(size_t)row * 1024 + col] = hnew;
      hbfout[(size_t)row * 1024 + col] = __float2bfloat16(hnew);
    }
  }
}

extern "C" void kernel_launch(void* const* d_in, const int* in_sizes, int n_in,
                              void* d_out, int out_size, void* d_ws, size_t ws_size,
                              hipStream_t stream) {
  (void)in_sizes; (void)n_in; (void)out_size;
  const float* z = (const float*)d_in[0];
  const float* trueinp = (const float*)d_in[1];
  const int* tfmask = (const int*)d_in[2];
  const float* fc_w = (const float*)d_in[3];
  const float* fc_b = (const float*)d_in[4];
  const float* ln_w = (const float*)d_in[5];
  const float* ln_b = (const float*)d_in[6];
  const float* w_ih = (const float*)d_in[7];
  const float* b_ih = (const float*)d_in[8];
  const float* w_hh = (const float*)d_in[9];
  const float* b_hh = (const float*)d_in[10];
  float* out = (float*)d_out;

  char* ws = (char*)d_ws;
  size_t o = 0;
  float* xraw = (float*)(ws + o); o += (size_t)2048 * 1024 * 4;
  float* h0f  = (float*)(ws + o); o += (size_t)2048 * 1024 * 4;
  unsigned short* gib = (unsigned short*)(ws + o); o += (size_t)2048 * 3072 * 2;
  bf16* h0b   = (bf16*)(ws + o);  o += (size_t)2048 * 1024 * 2;
  bf16* hbf0  = (bf16*)(ws + o);  o += (size_t)2048 * 1024 * 2;
  bf16* hbf1  = (bf16*)(ws + o);  o += (size_t)2048 * 1024 * 2;
  bf16* whhb  = (bf16*)(ws + o);  o += (size_t)3072 * 1024 * 2;
  bf16* whf   = (bf16*)(ws + o);  o += (size_t)3072 * 256 * 2;
  bf16* trueb = (bf16*)(ws + o);  o += (size_t)2048 * TSTEPS * 256 * 2;
  bf16* hbt   = (bf16*)(ws + o);
  const size_t need_hbt = o + (size_t)TSTEPS * 2048 * 1024 * 2;
  const bool use_hbt = (ws_size >= need_hbt);
  bf16* hbt_arg = use_hbt ? hbt : nullptr;

  convw_kernel<<<768, 256, 0, stream>>>(w_hh, (unsigned short*)whhb, (unsigned short*)whf);
  conv_kernel<<<2048, 256, 0, stream>>>(trueinp, (unsigned short*)trueb, 2048 * TSTEPS * 256 / 4);

  gemm_fc_kernel<<<dim3(16, 16), 256, 0, stream>>>(z, fc_w, fc_b, xraw);
  ln_kernel<<<2048, 256, 0, stream>>>(xraw, ln_w, ln_b, h0b, h0f);
  gemm_gi_kernel<<<dim3(16, 32), 512, 0, stream>>>(h0b, w_ih, b_ih, gib);

  batch_pair_kernel<<<dim3(16, 32, TSTEPS / 2), 512, 0, stream>>>(trueb, tfmask, whf,
                                                                  b_hh, gib, out, hbt_arg);

  level1b_kernel<<<dim3(512, TSTEPS), 512, 0, stream>>>(h0b, h0f, hbt_arg, tfmask, whhb,
                                                        b_hh, gib, out);

  for (int t = 1; t < TSTEPS; ++t) {
    bf16* hw = (t & 1) ? hbf1 : hbf0;
    const bf16* hr = (t & 1) ? hbf0 : hbf1;
    const float* prev = out + (size_t)(t - 1) * 2048 * 1024;
    step_kernel<<<512, 512, 0, stream>>>(prev, hr, hw, tfmask, whhb, b_hh, gib, out, t);
  }
}